// Round 2
// baseline (1558.682 us; speedup 1.0000x reference)
//
#include <hip/hip_runtime.h>
#include <hip/hip_bf16.h>
#include <math.h>

// Problem constants (fixed by the reference)
#define NN 50000      // nodes
#define NE 800000     // edges
#define HIDC 128
#define OUTC_FINAL 64

__device__ __forceinline__ float gelu_f(float x) {
    // tanh-approximate gelu (jax.nn.gelu approximate=True)
    float u = 0.7978845608028654f * (x + 0.044715f * x * x * x);
    return 0.5f * x * (1.0f + tanhf(u));
}

// ---------------- CSR build ----------------

__global__ void k_zero(int* p, int n) {
    int i = blockIdx.x * blockDim.x + threadIdx.x;
    if (i < n) p[i] = 0;
}

__global__ void k_hist(const int* __restrict__ dstv, int* __restrict__ deg) {
    int e = blockIdx.x * blockDim.x + threadIdx.x;
    if (e < NE) atomicAdd(&deg[dstv[e]], 1);
}

// single-block exclusive scan over deg[0..NN) -> rowstart, cursor; rowstart[NN]=NE
__global__ __launch_bounds__(1024) void k_scan(const int* __restrict__ deg,
                                               int* __restrict__ rowstart,
                                               int* __restrict__ cursor) {
    __shared__ int sh[1024];
    int t = threadIdx.x;
    int running = 0;
    for (int base = 0; base < NN; base += 1024) {
        int i = base + t;
        int v = (i < NN) ? deg[i] : 0;
        sh[t] = v;
        __syncthreads();
        for (int off = 1; off < 1024; off <<= 1) {
            int add = (t >= off) ? sh[t - off] : 0;
            __syncthreads();
            sh[t] += add;
            __syncthreads();
        }
        int incl = sh[t];
        int excl = incl - v;
        if (i < NN) { rowstart[i] = running + excl; cursor[i] = running + excl; }
        int tot = sh[1023];
        __syncthreads();
        running += tot;
    }
    if (t == 0) rowstart[NN] = running;
}

// scatter edges into dst-sorted records: {src, a0, a1, a2 (fp32 bits)}
__global__ void k_scatter(const int* __restrict__ srcv, const int* __restrict__ dstv,
                          const float* __restrict__ eattr, int* __restrict__ cursor,
                          int4* __restrict__ rec) {
    int e = blockIdx.x * blockDim.x + threadIdx.x;
    if (e >= NE) return;
    int dst = dstv[e];
    int pos = atomicAdd(&cursor[dst], 1);
    int4 r;
    r.x = srcv[e];
    r.y = __float_as_int(eattr[e * 3 + 0]);
    r.z = __float_as_int(eattr[e * 3 + 1]);
    r.w = __float_as_int(eattr[e * 3 + 2]);
    rec[pos] = r;
}

// ---------------- Node GEMM: out[n, c] = act(sum_k X[n,k] * W[c,k] + b[c]) (+res) ----------------
// Tile: 16 rows x 64 cols, 256 threads, K=128 fully resident in LDS.
// LDS stride 129 -> worst aliasing 2-way (free on gfx950, m136).

template <int OUTC, bool BIAS, bool GELU, bool RES>
__global__ __launch_bounds__(256) void k_gemm(const float* __restrict__ X, const float* __restrict__ W,
                                              const float* __restrict__ bias,
                                              const float* __restrict__ res,
                                              float* __restrict__ out) {
    __shared__ float xs[16][129];
    __shared__ float ws[64][129];
    int t = threadIdx.x;
    int rbase = blockIdx.x * 16;
    int cbase = blockIdx.y * 64;

    // X tile: 16x128 fp32 = 512 float4; 2 per thread, coalesced.
#pragma unroll
    for (int i = 0; i < 2; ++i) {
        int u = t + i * 256;
        int row = u >> 5;        // 0..15
        int c4 = (u & 31) * 4;   // 0..124
        float4 p = *reinterpret_cast<const float4*>(X + (size_t)(rbase + row) * 128 + c4);
        xs[row][c4 + 0] = p.x; xs[row][c4 + 1] = p.y;
        xs[row][c4 + 2] = p.z; xs[row][c4 + 3] = p.w;
    }
    // W tile: 64x128 fp32 = 2048 float4; 8 per thread.
#pragma unroll
    for (int i = 0; i < 8; ++i) {
        int u = t + i * 256;
        int row = u >> 5;        // 0..63
        int c4 = (u & 31) * 4;
        float4 p = *reinterpret_cast<const float4*>(W + (size_t)(cbase + row) * 128 + c4);
        ws[row][c4 + 0] = p.x; ws[row][c4 + 1] = p.y;
        ws[row][c4 + 2] = p.z; ws[row][c4 + 3] = p.w;
    }
    __syncthreads();

    int r2 = t >> 5;  // 0..7 -> rows r2*2 + {0,1}
    int c2 = t & 31;  // 0..31 -> cols c2*2 + {0,1}
    float acc00 = 0.f, acc01 = 0.f, acc10 = 0.f, acc11 = 0.f;
#pragma unroll 8
    for (int k = 0; k < 128; ++k) {
        float x0 = xs[r2 * 2 + 0][k];
        float x1 = xs[r2 * 2 + 1][k];
        float w0 = ws[c2 * 2 + 0][k];
        float w1 = ws[c2 * 2 + 1][k];
        acc00 += x0 * w0; acc01 += x0 * w1;
        acc10 += x1 * w0; acc11 += x1 * w1;
    }
    float accs[2][2] = {{acc00, acc01}, {acc10, acc11}};
#pragma unroll
    for (int i = 0; i < 2; ++i) {
#pragma unroll
        for (int j = 0; j < 2; ++j) {
            int row = rbase + r2 * 2 + i;
            int col = cbase + c2 * 2 + j;
            float v = accs[i][j];
            if (BIAS) v += bias[col];
            if (GELU) v = gelu_f(v);
            if (RES) v += res[(size_t)row * OUTC + col];
            out[(size_t)row * OUTC + col] = v;
        }
    }
}

// ---------------- TransformerConv aggregation (CSR, online softmax) ----------------
// One block (128 threads) per node; thread t -> head h=t>>5, dim d=t&31.
// out[n,t] = softmax-agg(v) + skip[n,t]. out must not alias qb/kb/vb/sb.

__global__ __launch_bounds__(128) void k_conv(const int* __restrict__ rowstart,
                                              const int4* __restrict__ rec,
                                              const float* __restrict__ qb, const float* __restrict__ kb,
                                              const float* __restrict__ vb, const float* __restrict__ sb,
                                              const float* __restrict__ We, float* __restrict__ out) {
    int n = blockIdx.x;
    int t = threadIdx.x;
    float qv = qb[(size_t)n * 128 + t];
    float we0 = We[t * 3 + 0];
    float we1 = We[t * 3 + 1];
    float we2 = We[t * 3 + 2];
    int e0 = rowstart[n], e1 = rowstart[n + 1];
    float m = -3.0e38f, ssum = 0.f, acc = 0.f;
    for (int e = e0; e < e1; ++e) {
        int4 r = rec[e];
        int src = r.x;
        float ev = __int_as_float(r.y) * we0 + __int_as_float(r.z) * we1 + __int_as_float(r.w) * we2;
        float kk = kb[(size_t)src * 128 + t] + ev;
        float part = qv * kk;
        part += __shfl_xor(part, 16);
        part += __shfl_xor(part, 8);
        part += __shfl_xor(part, 4);
        part += __shfl_xor(part, 2);
        part += __shfl_xor(part, 1);
        float alpha = part * 0.17677669529663687f;  // 1/sqrt(32)
        float vv = vb[(size_t)src * 128 + t] + ev;
        float mn = fmaxf(m, alpha);
        float sc = __expf(m - mn);   // first iter: underflows to 0
        float p = __expf(alpha - mn);
        acc = acc * sc + p * vv;
        ssum = ssum * sc + p;
        m = mn;
    }
    float o = acc / fmaxf(ssum, 1e-16f) + sb[(size_t)n * 128 + t];
    out[(size_t)n * 128 + t] = o;
}

// ---------------- launcher ----------------

extern "C" void kernel_launch(void* const* d_in, const int* in_sizes, int n_in,
                              void* d_out, int out_size, void* d_ws, size_t ws_size,
                              hipStream_t stream) {
    const float* x = (const float*)d_in[0];
    const int* ei = (const int*)d_in[1];
    const float* eattr = (const float*)d_in[2];
    const float* Wq1 = (const float*)d_in[3];
    const float* Wk1 = (const float*)d_in[4];
    const float* Wv1 = (const float*)d_in[5];
    const float* We1 = (const float*)d_in[6];
    const float* Ws1 = (const float*)d_in[7];
    const float* M1a = (const float*)d_in[8];
    const float* b1a = (const float*)d_in[9];
    const float* M1b = (const float*)d_in[10];
    const float* b1b = (const float*)d_in[11];
    const float* Wq2 = (const float*)d_in[12];
    const float* Wk2 = (const float*)d_in[13];
    const float* Wv2 = (const float*)d_in[14];
    const float* We2 = (const float*)d_in[15];
    const float* Ws2 = (const float*)d_in[16];
    const float* M2a = (const float*)d_in[17];
    const float* b2a = (const float*)d_in[18];
    const float* M2b = (const float*)d_in[19];
    const float* b2b = (const float*)d_in[20];
    const float* Wf1 = (const float*)d_in[21];
    const float* bf1 = (const float*)d_in[22];
    const float* Wf2 = (const float*)d_in[23];
    const float* bf2 = (const float*)d_in[24];

    char* ws = (char*)d_ws;
    size_t off = 0;
    auto alloc = [&](size_t bytes) -> void* {
        void* p = ws + off;
        off = (off + bytes + 255) & ~(size_t)255;
        return p;
    };
    int* deg = (int*)alloc((size_t)NN * 4);
    int* rowstart = (int*)alloc((size_t)(NN + 1) * 4);
    int* cursor = (int*)alloc((size_t)NN * 4);
    int4* rec = (int4*)alloc((size_t)NE * 16);
    const size_t NODEB = (size_t)NN * 128 * sizeof(float);
    float* B0 = (float*)alloc(NODEB);
    float* B1 = (float*)alloc(NODEB);
    float* B2 = (float*)alloc(NODEB);
    float* B3 = (float*)alloc(NODEB);
    float* B4 = (float*)alloc(NODEB);

    const int* srcv = ei;
    const int* dstv = ei + NE;

    // CSR build (shared by both conv layers)
    k_zero<<<(NN + 255) / 256, 256, 0, stream>>>(deg, NN);
    k_hist<<<(NE + 255) / 256, 256, 0, stream>>>(dstv, deg);
    k_scan<<<1, 1024, 0, stream>>>(deg, rowstart, cursor);
    k_scatter<<<(NE + 255) / 256, 256, 0, stream>>>(srcv, dstv, eattr, cursor, rec);

    dim3 blk(256);
    dim3 g128(NN / 16, 2);  // 50000/16 = 3125 exact
    dim3 g64(NN / 16, 1);

    // ----- layer 1 conv: q,k,v,skip from x -----
    k_gemm<128, false, false, false><<<g128, blk, 0, stream>>>(x, Wq1, nullptr, nullptr, B0);
    k_gemm<128, false, false, false><<<g128, blk, 0, stream>>>(x, Wk1, nullptr, nullptr, B1);
    k_gemm<128, false, false, false><<<g128, blk, 0, stream>>>(x, Wv1, nullptr, nullptr, B2);
    k_gemm<128, false, false, false><<<g128, blk, 0, stream>>>(x, Ws1, nullptr, nullptr, B3);
    k_conv<<<NN, 128, 0, stream>>>(rowstart, rec, B0, B1, B2, B3, We1, B4);  // H1 = B4
    // ----- layer 1 MLP with residual: H2 = H1 + gelu(gelu(H1@M1a+b1a)@M1b+b1b) -----
    k_gemm<128, true, true, false><<<g128, blk, 0, stream>>>(B4, M1a, b1a, nullptr, B0);  // T1 = B0
    k_gemm<128, true, true, true><<<g128, blk, 0, stream>>>(B0, M1b, b1b, B4, B1);        // H2 = B1

    // ----- layer 2 conv: q,k,v,skip from H2 -----
    k_gemm<128, false, false, false><<<g128, blk, 0, stream>>>(B1, Wq2, nullptr, nullptr, B2);
    k_gemm<128, false, false, false><<<g128, blk, 0, stream>>>(B1, Wk2, nullptr, nullptr, B3);
    k_gemm<128, false, false, false><<<g128, blk, 0, stream>>>(B1, Wv2, nullptr, nullptr, B0);
    k_gemm<128, false, false, false><<<g128, blk, 0, stream>>>(B1, Ws2, nullptr, nullptr, B4);
    k_conv<<<NN, 128, 0, stream>>>(rowstart, rec, B2, B3, B0, B4, We2, B1);  // H3 = B1
    // ----- layer 2 MLP: H4 = H3 + gelu(gelu(H3@M2a+b2a)@M2b+b2b) -----
    k_gemm<128, true, true, false><<<g128, blk, 0, stream>>>(B1, M2a, b2a, nullptr, B2);  // T2 = B2
    k_gemm<128, true, true, true><<<g128, blk, 0, stream>>>(B2, M2b, b2b, B1, B3);        // H4 = B3

    // ----- final MLP: out = gelu(gelu(H4@Wf1+bf1)@Wf2+bf2) -----
    k_gemm<128, true, true, false><<<g128, blk, 0, stream>>>(B3, Wf1, bf1, nullptr, B0);  // F1 = B0
    k_gemm<64, true, true, false><<<g64, blk, 0, stream>>>(B0, Wf2, bf2, nullptr, (float*)d_out);
}

// Round 3
// 873.362 us; speedup vs baseline: 1.7847x; 1.7847x over previous
//
#include <hip/hip_runtime.h>
#include <hip/hip_bf16.h>
#include <math.h>

// Problem constants (fixed by the reference)
#define NN 50000
#define NE 800000
#define NPAD 50048   // 782 * 64 — padded node-row count for tail-free GEMM tiles

typedef unsigned short u16;
typedef __attribute__((ext_vector_type(8))) short short8;   // 8 bf16 = 4 VGPRs (MFMA A/B frag)
typedef __attribute__((ext_vector_type(4))) float float4v;  // MFMA C/D frag

__device__ __forceinline__ float us2f(u16 u) { return __uint_as_float(((unsigned)u) << 16); }
__device__ __forceinline__ u16 f2us(float f) {   // fp32 -> bf16 (RNE)
    unsigned x = __float_as_uint(f);
    return (u16)((x + 0x7FFFu + ((x >> 16) & 1u)) >> 16);
}

__device__ __forceinline__ float gelu_f(float x) {
    // tanh-approximate gelu (jax.nn.gelu approximate=True)
    float u = 0.7978845608028654f * (x + 0.044715f * x * x * x);
    return 0.5f * x * (1.0f + tanhf(u));
}

// ---------------- CSR build ----------------

__global__ void k_zero(int* p, int n) {
    int i = blockIdx.x * blockDim.x + threadIdx.x;
    if (i < n) p[i] = 0;
}

__global__ void k_hist(const int* __restrict__ dstv, int* __restrict__ deg) {
    int e = blockIdx.x * blockDim.x + threadIdx.x;
    if (e < NE) atomicAdd(&deg[dstv[e]], 1);
}

__global__ __launch_bounds__(1024) void k_scan(const int* __restrict__ deg,
                                               int* __restrict__ rowstart,
                                               int* __restrict__ cursor) {
    __shared__ int sh[1024];
    int t = threadIdx.x;
    int running = 0;
    for (int base = 0; base < NN; base += 1024) {
        int i = base + t;
        int v = (i < NN) ? deg[i] : 0;
        sh[t] = v;
        __syncthreads();
        for (int off = 1; off < 1024; off <<= 1) {
            int add = (t >= off) ? sh[t - off] : 0;
            __syncthreads();
            sh[t] += add;
            __syncthreads();
        }
        int incl = sh[t];
        int excl = incl - v;
        if (i < NN) { rowstart[i] = running + excl; cursor[i] = running + excl; }
        int tot = sh[1023];
        __syncthreads();
        running += tot;
    }
    if (t == 0) rowstart[NN] = running;
}

__global__ void k_scatter(const int* __restrict__ srcv, const int* __restrict__ dstv,
                          const float* __restrict__ eattr, int* __restrict__ cursor,
                          int4* __restrict__ rec) {
    int e = blockIdx.x * blockDim.x + threadIdx.x;
    if (e >= NE) return;
    int dst = dstv[e];
    int pos = atomicAdd(&cursor[dst], 1);
    int4 r;
    r.x = srcv[e];
    r.y = __float_as_int(eattr[e * 3 + 0]);
    r.z = __float_as_int(eattr[e * 3 + 1]);
    r.w = __float_as_int(eattr[e * 3 + 2]);
    rec[pos] = r;
}

// ---------------- dtype conversion ----------------

// x fp32 [NN,128] -> bf16 [NPAD,128], pad rows zeroed. One thread = 4 elems.
__global__ void k_cvt_x(const float* __restrict__ x, u16* __restrict__ xb) {
    int q = blockIdx.x * blockDim.x + threadIdx.x;
    int base = q * 4;
    if (base >= NPAD * 128) return;
    ushort4 o;
    if (base < NN * 128) {
        float4 p = *reinterpret_cast<const float4*>(x + base);
        o.x = f2us(p.x); o.y = f2us(p.y); o.z = f2us(p.z); o.w = f2us(p.w);
    } else {
        o.x = o.y = o.z = o.w = 0;
    }
    *reinterpret_cast<ushort4*>(xb + base) = o;
}

// one-time fp32->bf16 conversion of all weight matrices
struct CvtEnt { const float* s; u16* d; int n; };
struct CvtTab { CvtEnt e[14]; };
__global__ void k_cvt_w(CvtTab tab) {
    CvtEnt E = tab.e[blockIdx.x];
    for (int i = threadIdx.x; i < E.n; i += blockDim.x) E.d[i] = f2us(E.s[i]);
}

// ---------------- MFMA GEMM: out[n,c] = act(sum_k A[n,k]*W[c,k] + b[c]) (+res) ----------------
// A: bf16 [NPAD,128]. W: bf16 [NTILES*16,128]. Block = 4 waves; block computes 64 rows
// x NTILES*16 cols; wave w handles rows [blk*64 + w*16, +16). K=128 = 4 MFMA chunks,
// a-frags held in VGPRs, weights served from L1 (32 KB bf16 fits).
// mfma_f32_16x16x32_bf16: A lane l holds A[m=l&15][k=(l>>4)*8+j]; B lane l holds
// W[c=l&15][k=(l>>4)*8+j]; D lane l reg r -> row=(l>>4)*4+r, col=l&15 (m89-verified).

template <int NTILES, bool BIAS, bool GELU, bool RES, bool F32OUT>
__global__ __launch_bounds__(256) void k_gemm_mfma(const u16* __restrict__ A,
                                                   const u16* __restrict__ W,
                                                   const float* __restrict__ bias,
                                                   const u16* __restrict__ res,
                                                   void* __restrict__ outp,
                                                   int ostride, int ocol) {
    int l = threadIdx.x & 63;
    int w = threadIdx.x >> 6;
    int m = l & 15;
    int kb = l >> 4;                       // 0..3
    int r0 = blockIdx.x * 64 + w * 16;

    const short8* arow = reinterpret_cast<const short8*>(A + (size_t)(r0 + m) * 128);
    short8 a0 = arow[kb + 0];
    short8 a1 = arow[kb + 4];
    short8 a2 = arow[kb + 8];
    short8 a3 = arow[kb + 12];

    for (int tt = 0; tt < NTILES; ++tt) {
        const short8* wrow = reinterpret_cast<const short8*>(W + (size_t)(tt * 16 + m) * 128);
        short8 b0 = wrow[kb + 0];
        short8 b1 = wrow[kb + 4];
        short8 b2 = wrow[kb + 8];
        short8 b3 = wrow[kb + 12];
        float4v acc = {0.f, 0.f, 0.f, 0.f};
        acc = __builtin_amdgcn_mfma_f32_16x16x32_bf16(a0, b0, acc, 0, 0, 0);
        acc = __builtin_amdgcn_mfma_f32_16x16x32_bf16(a1, b1, acc, 0, 0, 0);
        acc = __builtin_amdgcn_mfma_f32_16x16x32_bf16(a2, b2, acc, 0, 0, 0);
        acc = __builtin_amdgcn_mfma_f32_16x16x32_bf16(a3, b3, acc, 0, 0, 0);

        float bv = BIAS ? bias[tt * 16 + m] : 0.f;
#pragma unroll
        for (int r = 0; r < 4; ++r) {
            int grow = r0 + kb * 4 + r;
            float v = acc[r] + bv;
            if (GELU) v = gelu_f(v);
            if (RES) v += us2f(res[(size_t)grow * 128 + tt * 16 + m]);
            if (F32OUT) {
                if (grow < NN)
                    reinterpret_cast<float*>(outp)[(size_t)grow * (NTILES * 16) + tt * 16 + m] = v;
            } else {
                reinterpret_cast<u16*>(outp)[(size_t)grow * ostride + ocol + tt * 16 + m] = f2us(v);
            }
        }
    }
}

// ---------------- TransformerConv aggregation (CSR, online softmax, bf16 qkvs) ----------------
// qkvs layout per node row (stride 512): [0,128)=q [128,256)=k [256,384)=v [384,512)=skip.
// One block (128 threads) per node; thread t -> head h=t>>5, dim d=t&31.

__global__ __launch_bounds__(128) void k_conv(const int* __restrict__ rowstart,
                                              const int4* __restrict__ rec,
                                              const u16* __restrict__ qkvs,
                                              const float* __restrict__ We,
                                              u16* __restrict__ out) {
    int n = blockIdx.x;
    int t = threadIdx.x;
    float qv = us2f(qkvs[(size_t)n * 512 + t]);
    float we0 = We[t * 3 + 0];
    float we1 = We[t * 3 + 1];
    float we2 = We[t * 3 + 2];
    int e0 = rowstart[n], e1 = rowstart[n + 1];
    float m = -3.0e38f, ssum = 0.f, acc = 0.f;
    for (int e = e0; e < e1; ++e) {
        int4 r = rec[e];
        const u16* kvrow = qkvs + (size_t)r.x * 512;
        float kk = us2f(kvrow[128 + t]);
        float vv = us2f(kvrow[256 + t]);
        float ev = __int_as_float(r.y) * we0 + __int_as_float(r.z) * we1 + __int_as_float(r.w) * we2;
        kk += ev;
        vv += ev;
        float part = qv * kk;
        part += __shfl_xor(part, 16);
        part += __shfl_xor(part, 8);
        part += __shfl_xor(part, 4);
        part += __shfl_xor(part, 2);
        part += __shfl_xor(part, 1);
        float alpha = part * 0.17677669529663687f;  // 1/sqrt(32)
        float mn = fmaxf(m, alpha);
        float sc = __expf(m - mn);
        float p = __expf(alpha - mn);
        acc = acc * sc + p * vv;
        ssum = ssum * sc + p;
        m = mn;
    }
    float o = acc / fmaxf(ssum, 1e-16f) + us2f(qkvs[(size_t)n * 512 + 384 + t]);
    out[(size_t)n * 128 + t] = f2us(o);
}

// ---------------- launcher ----------------

extern "C" void kernel_launch(void* const* d_in, const int* in_sizes, int n_in,
                              void* d_out, int out_size, void* d_ws, size_t ws_size,
                              hipStream_t stream) {
    const float* x = (const float*)d_in[0];
    const int* ei = (const int*)d_in[1];
    const float* eattr = (const float*)d_in[2];
    const float* Wq1 = (const float*)d_in[3];
    const float* Wk1 = (const float*)d_in[4];
    const float* Wv1 = (const float*)d_in[5];
    const float* We1 = (const float*)d_in[6];
    const float* Ws1 = (const float*)d_in[7];
    const float* M1a = (const float*)d_in[8];
    const float* b1a = (const float*)d_in[9];
    const float* M1b = (const float*)d_in[10];
    const float* b1b = (const float*)d_in[11];
    const float* Wq2 = (const float*)d_in[12];
    const float* Wk2 = (const float*)d_in[13];
    const float* Wv2 = (const float*)d_in[14];
    const float* We2 = (const float*)d_in[15];
    const float* Ws2 = (const float*)d_in[16];
    const float* M2a = (const float*)d_in[17];
    const float* b2a = (const float*)d_in[18];
    const float* M2b = (const float*)d_in[19];
    const float* b2b = (const float*)d_in[20];
    const float* Wf1 = (const float*)d_in[21];
    const float* bf1 = (const float*)d_in[22];
    const float* Wf2 = (const float*)d_in[23];
    const float* bf2 = (const float*)d_in[24];

    char* ws = (char*)d_ws;
    size_t off = 0;
    auto alloc = [&](size_t bytes) -> void* {
        void* p = ws + off;
        off = (off + bytes + 255) & ~(size_t)255;
        return p;
    };
    int* deg = (int*)alloc((size_t)NN * 4);
    int* rowstart = (int*)alloc((size_t)(NN + 1) * 4);
    int* cursor = (int*)alloc((size_t)NN * 4);
    int4* rec = (int4*)alloc((size_t)NE * 16);
    u16* Xb = (u16*)alloc((size_t)NPAD * 128 * 2);
    u16* QKVS = (u16*)alloc((size_t)NPAD * 512 * 2);
    u16* Ha = (u16*)alloc((size_t)NPAD * 128 * 2);
    u16* Hb = (u16*)alloc((size_t)NPAD * 128 * 2);
    u16* Hc = (u16*)alloc((size_t)NPAD * 128 * 2);
    u16* WB[14];
    const int wsz[14] = {16384, 16384, 16384, 16384, 16384, 16384, 16384,
                         16384, 16384, 16384, 16384, 16384, 16384, 8192};
    for (int i = 0; i < 14; ++i) WB[i] = (u16*)alloc((size_t)wsz[i] * 2);

    const int* srcv = ei;
    const int* dstv = ei + NE;

    // CSR build (shared by both conv layers)
    k_zero<<<(NN + 255) / 256, 256, 0, stream>>>(deg, NN);
    k_hist<<<(NE + 255) / 256, 256, 0, stream>>>(dstv, deg);
    k_scan<<<1, 1024, 0, stream>>>(deg, rowstart, cursor);
    k_scatter<<<(NE + 255) / 256, 256, 0, stream>>>(srcv, dstv, eattr, cursor, rec);

    // dtype conversions
    k_cvt_x<<<(NPAD * 128 / 4 + 255) / 256, 256, 0, stream>>>(x, Xb);
    CvtTab tab;
    const float* wsrc[14] = {Wq1, Wk1, Wv1, Ws1, M1a, M1b, Wq2, Wk2, Wv2, Ws2, M2a, M2b, Wf1, Wf2};
    for (int i = 0; i < 14; ++i) { tab.e[i].s = wsrc[i]; tab.e[i].d = WB[i]; tab.e[i].n = wsz[i]; }
    k_cvt_w<<<14, 256, 0, stream>>>(tab);

    dim3 blk(256);
    dim3 grd(NPAD / 64);  // 782

    // ----- layer 1 conv -----
    k_gemm_mfma<8, false, false, false, false><<<grd, blk, 0, stream>>>(Xb, WB[0], nullptr, nullptr, QKVS, 512, 0);
    k_gemm_mfma<8, false, false, false, false><<<grd, blk, 0, stream>>>(Xb, WB[1], nullptr, nullptr, QKVS, 512, 128);
    k_gemm_mfma<8, false, false, false, false><<<grd, blk, 0, stream>>>(Xb, WB[2], nullptr, nullptr, QKVS, 512, 256);
    k_gemm_mfma<8, false, false, false, false><<<grd, blk, 0, stream>>>(Xb, WB[3], nullptr, nullptr, QKVS, 512, 384);
    k_conv<<<NN, 128, 0, stream>>>(rowstart, rec, QKVS, We1, Ha);  // H1 = Ha
    // ----- layer 1 MLP: H2 = H1 + gelu(gelu(H1@M1a+b1a)@M1b+b1b) -----
    k_gemm_mfma<8, true, true, false, false><<<grd, blk, 0, stream>>>(Ha, WB[4], b1a, nullptr, Hb, 128, 0);
    k_gemm_mfma<8, true, true, true, false><<<grd, blk, 0, stream>>>(Hb, WB[5], b1b, Ha, Hc, 128, 0);  // H2 = Hc

    // ----- layer 2 conv -----
    k_gemm_mfma<8, false, false, false, false><<<grd, blk, 0, stream>>>(Hc, WB[6], nullptr, nullptr, QKVS, 512, 0);
    k_gemm_mfma<8, false, false, false, false><<<grd, blk, 0, stream>>>(Hc, WB[7], nullptr, nullptr, QKVS, 512, 128);
    k_gemm_mfma<8, false, false, false, false><<<grd, blk, 0, stream>>>(Hc, WB[8], nullptr, nullptr, QKVS, 512, 256);
    k_gemm_mfma<8, false, false, false, false><<<grd, blk, 0, stream>>>(Hc, WB[9], nullptr, nullptr, QKVS, 512, 384);
    k_conv<<<NN, 128, 0, stream>>>(rowstart, rec, QKVS, We2, Ha);  // H3 = Ha
    // ----- layer 2 MLP: H4 = H3 + gelu(gelu(H3@M2a+b2a)@M2b+b2b) -----
    k_gemm_mfma<8, true, true, false, false><<<grd, blk, 0, stream>>>(Ha, WB[10], b2a, nullptr, Hb, 128, 0);
    k_gemm_mfma<8, true, true, true, false><<<grd, blk, 0, stream>>>(Hb, WB[11], b2b, Ha, Hc, 128, 0);  // H4 = Hc

    // ----- final MLP -----
    k_gemm_mfma<8, true, true, false, false><<<grd, blk, 0, stream>>>(Hc, WB[12], bf1, nullptr, Hb, 128, 0);
    k_gemm_mfma<4, true, true, false, true><<<grd, blk, 0, stream>>>(Hb, WB[13], bf2, nullptr, d_out, 64, 0);
}

// Round 4
// 731.683 us; speedup vs baseline: 2.1303x; 1.1936x over previous
//
#include <hip/hip_runtime.h>
#include <hip/hip_bf16.h>
#include <math.h>

// Problem constants (fixed by the reference)
#define NN 50000
#define NE 800000
#define NPAD 50048   // 782 * 64 — padded node-row count for tail-free GEMM tiles

typedef unsigned short u16;
typedef __attribute__((ext_vector_type(8))) short short8;   // 8 bf16 = 4 VGPRs (MFMA A/B frag)
typedef __attribute__((ext_vector_type(4))) float float4v;  // MFMA C/D frag

__device__ __forceinline__ float us2f(u16 u) { return __uint_as_float(((unsigned)u) << 16); }
__device__ __forceinline__ u16 f2us(float f) {   // fp32 -> bf16 (RNE)
    unsigned x = __float_as_uint(f);
    return (u16)((x + 0x7FFFu + ((x >> 16) & 1u)) >> 16);
}

__device__ __forceinline__ float gelu_f(float x) {
    float u = 0.7978845608028654f * (x + 0.044715f * x * x * x);
    return 0.5f * x * (1.0f + tanhf(u));
}

// ---------------- CSR build ----------------

__global__ void k_zero(int* p, int n) {
    int i = blockIdx.x * blockDim.x + threadIdx.x;
    if (i < n) p[i] = 0;
}

__global__ void k_hist(const int* __restrict__ dstv, int* __restrict__ deg) {
    int e = blockIdx.x * blockDim.x + threadIdx.x;
    if (e < NE) atomicAdd(&deg[dstv[e]], 1);
}

// single-block scan, wave-shuffle based: 3 barriers per 1024-chunk (was 30)
__global__ __launch_bounds__(1024) void k_scan(const int* __restrict__ deg,
                                               int* __restrict__ rowstart,
                                               int* __restrict__ cursor) {
    __shared__ int wsum[16];
    int t = threadIdx.x;
    int lane = t & 63;
    int wid = t >> 6;
    int running = 0;
    for (int base = 0; base < NN; base += 1024) {
        int i = base + t;
        int v = (i < NN) ? deg[i] : 0;
        int incl = v;
#pragma unroll
        for (int d = 1; d < 64; d <<= 1) {
            int tv = __shfl_up(incl, d);
            if (lane >= d) incl += tv;
        }
        if (lane == 63) wsum[wid] = incl;
        __syncthreads();
        if (wid == 0) {
            int wv = (lane < 16) ? wsum[lane] : 0;
            int wincl = wv;
#pragma unroll
            for (int d = 1; d < 16; d <<= 1) {
                int tv = __shfl_up(wincl, d);
                if (lane >= d) wincl += tv;
            }
            if (lane < 16) wsum[lane] = wincl;
        }
        __syncthreads();
        int woff = (wid > 0) ? wsum[wid - 1] : 0;
        int excl = running + woff + (incl - v);
        if (i < NN) { rowstart[i] = excl; cursor[i] = excl; }
        running += wsum[15];
        __syncthreads();   // protect wsum before next chunk overwrites
    }
    if (t == 0) rowstart[NN] = running;
}

__global__ void k_scatter(const int* __restrict__ srcv, const int* __restrict__ dstv,
                          const float* __restrict__ eattr, int* __restrict__ cursor,
                          int4* __restrict__ rec) {
    int e = blockIdx.x * blockDim.x + threadIdx.x;
    if (e >= NE) return;
    int dst = dstv[e];
    int pos = atomicAdd(&cursor[dst], 1);
    int4 r;
    r.x = srcv[e];
    r.y = __float_as_int(eattr[e * 3 + 0]);
    r.z = __float_as_int(eattr[e * 3 + 1]);
    r.w = __float_as_int(eattr[e * 3 + 2]);
    rec[pos] = r;
}

// ---------------- dtype conversion ----------------

__global__ void k_cvt_x(const float* __restrict__ x, u16* __restrict__ xb) {
    int q = blockIdx.x * blockDim.x + threadIdx.x;
    int base = q * 4;
    if (base >= NPAD * 128) return;
    ushort4 o;
    if (base < NN * 128) {
        float4 p = *reinterpret_cast<const float4*>(x + base);
        o.x = f2us(p.x); o.y = f2us(p.y); o.z = f2us(p.z); o.w = f2us(p.w);
    } else {
        o.x = o.y = o.z = o.w = 0;
    }
    *reinterpret_cast<ushort4*>(xb + base) = o;
}

struct CvtEnt { const float* s; u16* d; int n; };
struct CvtTab { CvtEnt e[14]; };
__global__ void k_cvt_w(CvtTab tab) {
    CvtEnt E = tab.e[blockIdx.x];
    for (int i = threadIdx.x; i < E.n; i += blockDim.x) E.d[i] = f2us(E.s[i]);
}

// ---------------- MFMA GEMM with LDS-staged coalesced epilogue ----------------
// A: bf16 [NPAD,128]. W: bf16 [GROUPS*TPG*16, 128] row-major (concat over groups).
// Block = 4 waves = 64 rows. Per group: compute TPG 16-col tiles -> stage bf16 in LDS
// -> cooperative uint4 (8 bf16) coalesced stores to out cols [g*TPG*16, ...).
// mfma_f32_16x16x32_bf16 layouts (m89-verified): A lane l: A[m=l&15][k=(l>>4)*8+j];
// D lane l reg r: row=(l>>4)*4+r, col=l&15.

template <int TPG, int GROUPS, bool BIAS, bool GELU, bool RES, bool F32OUT>
__global__ __launch_bounds__(256) void k_gemm2(const u16* __restrict__ A,
                                               const u16* __restrict__ W,
                                               const float* __restrict__ bias,
                                               const u16* __restrict__ res,
                                               void* __restrict__ outp,
                                               int ostride) {
    constexpr int C16 = TPG * 16;        // cols per group
    constexpr int LSTR = C16 + 8;        // LDS row stride (u16); keeps 16B alignment
    __shared__ u16 ctile[64 * LSTR];

    int l = threadIdx.x & 63;
    int w = threadIdx.x >> 6;
    int m = l & 15;
    int kb = l >> 4;                     // 0..3
    int r0 = blockIdx.x * 64;

    const short8* arow = reinterpret_cast<const short8*>(A + (size_t)(r0 + w * 16 + m) * 128);
    short8 a0 = arow[kb + 0];
    short8 a1 = arow[kb + 4];
    short8 a2 = arow[kb + 8];
    short8 a3 = arow[kb + 12];

    for (int g = 0; g < GROUPS; ++g) {
        if (g > 0) __syncthreads();      // LDS reuse guard
#pragma unroll
        for (int tt = 0; tt < TPG; ++tt) {
            int gt = g * TPG + tt;
            const short8* wrow = reinterpret_cast<const short8*>(W + (size_t)(gt * 16 + m) * 128);
            short8 b0 = wrow[kb + 0];
            short8 b1 = wrow[kb + 4];
            short8 b2 = wrow[kb + 8];
            short8 b3 = wrow[kb + 12];
            float4v acc = {0.f, 0.f, 0.f, 0.f};
            acc = __builtin_amdgcn_mfma_f32_16x16x32_bf16(a0, b0, acc, 0, 0, 0);
            acc = __builtin_amdgcn_mfma_f32_16x16x32_bf16(a1, b1, acc, 0, 0, 0);
            acc = __builtin_amdgcn_mfma_f32_16x16x32_bf16(a2, b2, acc, 0, 0, 0);
            acc = __builtin_amdgcn_mfma_f32_16x16x32_bf16(a3, b3, acc, 0, 0, 0);
            float bv = BIAS ? bias[gt * 16 + m] : 0.f;
#pragma unroll
            for (int r = 0; r < 4; ++r) {
                float v = acc[r] + bv;
                if (GELU) v = gelu_f(v);
                ctile[(w * 16 + kb * 4 + r) * LSTR + tt * 16 + m] = f2us(v);
            }
        }
        __syncthreads();
        // cooperative coalesced store: 64 rows x C16 cols, 8 bf16 per thread per iter
        constexpr int ITERS = (64 * C16) / (256 * 8);
#pragma unroll
        for (int it = 0; it < ITERS; ++it) {
            int q = (it * 256 + threadIdx.x) * 8;
            int row = q / C16;
            int col = q % C16;
            uint4 pk = *reinterpret_cast<const uint4*>(&ctile[row * LSTR + col]);
            const u16* pv = reinterpret_cast<const u16*>(&pk);
            int grow = r0 + row;
            if (F32OUT) {
                if (grow < NN) {
                    float* po = reinterpret_cast<float*>(outp) + (size_t)grow * ostride + col;
                    float4 o0, o1;
                    o0.x = us2f(pv[0]); o0.y = us2f(pv[1]); o0.z = us2f(pv[2]); o0.w = us2f(pv[3]);
                    o1.x = us2f(pv[4]); o1.y = us2f(pv[5]); o1.z = us2f(pv[6]); o1.w = us2f(pv[7]);
                    *reinterpret_cast<float4*>(po) = o0;
                    *reinterpret_cast<float4*>(po + 4) = o1;
                }
            } else {
                uint4 o = pk;
                if (RES) {
                    uint4 rk = *reinterpret_cast<const uint4*>(res + (size_t)grow * 128 + col);
                    const u16* pr = reinterpret_cast<const u16*>(&rk);
                    u16* pov = reinterpret_cast<u16*>(&o);
#pragma unroll
                    for (int j = 0; j < 8; ++j) pov[j] = f2us(us2f(pv[j]) + us2f(pr[j]));
                }
                *reinterpret_cast<uint4*>(reinterpret_cast<u16*>(outp) +
                                          (size_t)grow * ostride + g * C16 + col) = o;
            }
        }
    }
}

// ---------------- TransformerConv aggregation: 1 wave/node, float2/lane ----------------
// qkvs row (stride 512): [0,128)=q [128,256)=k [256,384)=v [384,512)=skip.
// Block = 256 threads = 4 waves = 4 nodes. Lane l: head h=l>>4, dim pair dp=l&15
// -> cols c0=h*32+2*dp, c0+1. Dot over 16 lanes via 4 shfl_xor (group-aligned).

__global__ __launch_bounds__(256) void k_conv(const int* __restrict__ rowstart,
                                              const int4* __restrict__ rec,
                                              const u16* __restrict__ qkvs,
                                              const float* __restrict__ We,
                                              u16* __restrict__ out) {
    int n = blockIdx.x * 4 + (threadIdx.x >> 6);
    int l = threadIdx.x & 63;
    int dp = l & 15;
    int c0 = (l >> 4) * 32 + dp * 2;
    const u16* qrow = qkvs + (size_t)n * 512;
    unsigned qu = *reinterpret_cast<const unsigned*>(qrow + c0);
    float q0 = us2f((u16)(qu & 0xffffu)), q1 = us2f((u16)(qu >> 16));
    float we00 = We[c0 * 3 + 0], we01 = We[c0 * 3 + 1], we02 = We[c0 * 3 + 2];
    float we10 = We[c0 * 3 + 3], we11 = We[c0 * 3 + 4], we12 = We[c0 * 3 + 5];
    int e0 = rowstart[n], e1 = rowstart[n + 1];
    float m = -3.0e38f, ss = 0.f, a0 = 0.f, a1 = 0.f;
    for (int e = e0; e < e1; ++e) {
        int4 r = rec[e];
        const u16* kv = qkvs + (size_t)r.x * 512;
        unsigned ku = *reinterpret_cast<const unsigned*>(kv + 128 + c0);
        unsigned vu = *reinterpret_cast<const unsigned*>(kv + 256 + c0);
        float ea0 = __int_as_float(r.y), ea1 = __int_as_float(r.z), ea2 = __int_as_float(r.w);
        float ev0 = ea0 * we00 + ea1 * we01 + ea2 * we02;
        float ev1 = ea0 * we10 + ea1 * we11 + ea2 * we12;
        float k0 = us2f((u16)(ku & 0xffffu)) + ev0, k1 = us2f((u16)(ku >> 16)) + ev1;
        float v0 = us2f((u16)(vu & 0xffffu)) + ev0, v1 = us2f((u16)(vu >> 16)) + ev1;
        float part = q0 * k0 + q1 * k1;
        part += __shfl_xor(part, 8);
        part += __shfl_xor(part, 4);
        part += __shfl_xor(part, 2);
        part += __shfl_xor(part, 1);
        float alpha = part * 0.17677669529663687f;  // 1/sqrt(32)
        float mn = fmaxf(m, alpha);
        float sc = __expf(m - mn);
        float p = __expf(alpha - mn);
        a0 = a0 * sc + p * v0;
        a1 = a1 * sc + p * v1;
        ss = ss * sc + p;
        m = mn;
    }
    float inv = 1.f / fmaxf(ss, 1e-16f);
    unsigned su = *reinterpret_cast<const unsigned*>(qrow + 384 + c0);
    float o0 = a0 * inv + us2f((u16)(su & 0xffffu));
    float o1 = a1 * inv + us2f((u16)(su >> 16));
    unsigned ou = (unsigned)f2us(o0) | ((unsigned)f2us(o1) << 16);
    *reinterpret_cast<unsigned*>(out + (size_t)n * 128 + c0) = ou;
}

// ---------------- launcher ----------------

extern "C" void kernel_launch(void* const* d_in, const int* in_sizes, int n_in,
                              void* d_out, int out_size, void* d_ws, size_t ws_size,
                              hipStream_t stream) {
    const float* x = (const float*)d_in[0];
    const int* ei = (const int*)d_in[1];
    const float* eattr = (const float*)d_in[2];
    const float* Wq1 = (const float*)d_in[3];
    const float* Wk1 = (const float*)d_in[4];
    const float* Wv1 = (const float*)d_in[5];
    const float* We1 = (const float*)d_in[6];
    const float* Ws1 = (const float*)d_in[7];
    const float* M1a = (const float*)d_in[8];
    const float* b1a = (const float*)d_in[9];
    const float* M1b = (const float*)d_in[10];
    const float* b1b = (const float*)d_in[11];
    const float* Wq2 = (const float*)d_in[12];
    const float* Wk2 = (const float*)d_in[13];
    const float* Wv2 = (const float*)d_in[14];
    const float* We2 = (const float*)d_in[15];
    const float* Ws2 = (const float*)d_in[16];
    const float* M2a = (const float*)d_in[17];
    const float* b2a = (const float*)d_in[18];
    const float* M2b = (const float*)d_in[19];
    const float* b2b = (const float*)d_in[20];
    const float* Wf1 = (const float*)d_in[21];
    const float* bf1 = (const float*)d_in[22];
    const float* Wf2 = (const float*)d_in[23];
    const float* bf2 = (const float*)d_in[24];

    char* ws = (char*)d_ws;
    size_t off = 0;
    auto alloc = [&](size_t bytes) -> void* {
        void* p = ws + off;
        off = (off + bytes + 255) & ~(size_t)255;
        return p;
    };
    int* deg = (int*)alloc((size_t)NN * 4);
    int* rowstart = (int*)alloc((size_t)(NN + 1) * 4);
    int* cursor = (int*)alloc((size_t)NN * 4);
    int4* rec = (int4*)alloc((size_t)NE * 16);
    u16* Xb = (u16*)alloc((size_t)NPAD * 128 * 2);
    u16* QKVS = (u16*)alloc((size_t)NPAD * 512 * 2);
    u16* Ha = (u16*)alloc((size_t)NPAD * 128 * 2);
    u16* Hb = (u16*)alloc((size_t)NPAD * 128 * 2);
    u16* Hc = (u16*)alloc((size_t)NPAD * 128 * 2);
    // weight order: [Wq1 Wk1 Wv1 Ws1][Wq2 Wk2 Wv2 Ws2] contiguous (fused QKVS), then MLPs
    u16* WB[14];
    const int wsz[14] = {16384, 16384, 16384, 16384, 16384, 16384, 16384,
                         16384, 16384, 16384, 16384, 16384, 16384, 8192};
    for (int i = 0; i < 14; ++i) WB[i] = (u16*)alloc((size_t)wsz[i] * 2);

    const int* srcv = ei;
    const int* dstv = ei + NE;

    // CSR build (shared by both conv layers)
    k_zero<<<(NN + 255) / 256, 256, 0, stream>>>(deg, NN);
    k_hist<<<(NE + 255) / 256, 256, 0, stream>>>(dstv, deg);
    k_scan<<<1, 1024, 0, stream>>>(deg, rowstart, cursor);
    k_scatter<<<(NE + 255) / 256, 256, 0, stream>>>(srcv, dstv, eattr, cursor, rec);

    // dtype conversions
    k_cvt_x<<<(NPAD * 128 / 4 + 255) / 256, 256, 0, stream>>>(x, Xb);
    CvtTab tab;
    const float* wsrc[14] = {Wq1, Wk1, Wv1, Ws1, Wq2, Wk2, Wv2, Ws2,
                             M1a, M1b, M2a, M2b, Wf1, Wf2};
    for (int i = 0; i < 14; ++i) { tab.e[i].s = wsrc[i]; tab.e[i].d = WB[i]; tab.e[i].n = wsz[i]; }
    k_cvt_w<<<14, 256, 0, stream>>>(tab);

    dim3 blk(256);
    dim3 grd(NPAD / 64);   // 782
    dim3 gconv(NN / 4);    // 12500

    // ----- layer 1 -----
    k_gemm2<8, 4, false, false, false, false><<<grd, blk, 0, stream>>>(Xb, WB[0], nullptr, nullptr, QKVS, 512);
    k_conv<<<gconv, blk, 0, stream>>>(rowstart, rec, QKVS, We1, Ha);                                  // H1 = Ha
    k_gemm2<8, 1, true, true, false, false><<<grd, blk, 0, stream>>>(Ha, WB[8], b1a, nullptr, Hb, 128);
    k_gemm2<8, 1, true, true, true, false><<<grd, blk, 0, stream>>>(Hb, WB[9], b1b, Ha, Hc, 128);     // H2 = Hc

    // ----- layer 2 -----
    k_gemm2<8, 4, false, false, false, false><<<grd, blk, 0, stream>>>(Hc, WB[4], nullptr, nullptr, QKVS, 512);
    k_conv<<<gconv, blk, 0, stream>>>(rowstart, rec, QKVS, We2, Ha);                                  // H3 = Ha
    k_gemm2<8, 1, true, true, false, false><<<grd, blk, 0, stream>>>(Ha, WB[10], b2a, nullptr, Hb, 128);
    k_gemm2<8, 1, true, true, true, false><<<grd, blk, 0, stream>>>(Hb, WB[11], b2b, Ha, Hc, 128);    // H4 = Hc

    // ----- final MLP -----
    k_gemm2<8, 1, true, true, false, false><<<grd, blk, 0, stream>>>(Hc, WB[12], bf1, nullptr, Hb, 128);
    k_gemm2<4, 1, true, true, false, true><<<grd, blk, 0, stream>>>(Hb, WB[13], bf2, nullptr, d_out, 64);
}

// Round 5
// 632.089 us; speedup vs baseline: 2.4659x; 1.1576x over previous
//
#include <hip/hip_runtime.h>
#include <hip/hip_bf16.h>
#include <math.h>

// Problem constants (fixed by the reference)
#define NN 50000
#define NE 800000
#define NPAD 50048   // 782 * 64 — tail-free GEMM tiles

typedef unsigned short u16;
typedef unsigned int u32;
typedef __attribute__((ext_vector_type(8))) short short8;   // 8 bf16 (MFMA A/B frag)
typedef __attribute__((ext_vector_type(4))) float float4v;  // MFMA C/D frag

__device__ __forceinline__ float us2f(u16 u) { return __uint_as_float(((unsigned)u) << 16); }
__device__ __forceinline__ float blo(u32 u) { return __uint_as_float(u << 16); }
__device__ __forceinline__ float bhi(u32 u) { return __uint_as_float(u & 0xffff0000u); }
__device__ __forceinline__ u16 f2us(float f) {   // fp32 -> bf16 RNE
    unsigned x = __float_as_uint(f);
    return (u16)((x + 0x7FFFu + ((x >> 16) & 1u)) >> 16);
}
// tanh-gelu via sigmoid identity: 0.5*(1+tanh(u)) = sigmoid(2u)
__device__ __forceinline__ float gelu_f(float x) {
    float p = x * x;
    float t = x * fmaf(p, 0.0713548162726f, 1.5957691216057308f);  // 2u
    float e = __expf(-t);
    return x * __builtin_amdgcn_rcpf(1.0f + e);
}

// ---------------- CSR build ----------------

__global__ void k_zero(int* p, int n) {
    int i = blockIdx.x * blockDim.x + threadIdx.x;
    if (i < n) p[i] = 0;
}

__global__ void k_hist(const int* __restrict__ dstv, int* __restrict__ deg) {
    int e = blockIdx.x * blockDim.x + threadIdx.x;
    if (e < NE) atomicAdd(&deg[dstv[e]], 1);
}

__global__ __launch_bounds__(1024) void k_scan(const int* __restrict__ deg,
                                               int* __restrict__ rowstart,
                                               int* __restrict__ cursor) {
    __shared__ int wsum[16];
    int t = threadIdx.x;
    int lane = t & 63;
    int wid = t >> 6;
    int running = 0;
    for (int base = 0; base < NN; base += 1024) {
        int i = base + t;
        int v = (i < NN) ? deg[i] : 0;
        int incl = v;
#pragma unroll
        for (int d = 1; d < 64; d <<= 1) {
            int tv = __shfl_up(incl, d);
            if (lane >= d) incl += tv;
        }
        if (lane == 63) wsum[wid] = incl;
        __syncthreads();
        if (wid == 0) {
            int wv = (lane < 16) ? wsum[lane] : 0;
            int wincl = wv;
#pragma unroll
            for (int d = 1; d < 16; d <<= 1) {
                int tv = __shfl_up(wincl, d);
                if (lane >= d) wincl += tv;
            }
            if (lane < 16) wsum[lane] = wincl;
        }
        __syncthreads();
        int woff = (wid > 0) ? wsum[wid - 1] : 0;
        int excl = running + woff + (incl - v);
        if (i < NN) { rowstart[i] = excl; cursor[i] = excl; }
        running += wsum[15];
        __syncthreads();
    }
    if (t == 0) rowstart[NN] = running;
}

__global__ void k_scatter(const int* __restrict__ srcv, const int* __restrict__ dstv,
                          const float* __restrict__ eattr, int* __restrict__ cursor,
                          int4* __restrict__ rec) {
    int e = blockIdx.x * blockDim.x + threadIdx.x;
    if (e >= NE) return;
    int dst = dstv[e];
    int pos = atomicAdd(&cursor[dst], 1);
    int4 r;
    r.x = srcv[e];
    r.y = __float_as_int(eattr[e * 3 + 0]);
    r.z = __float_as_int(eattr[e * 3 + 1]);
    r.w = __float_as_int(eattr[e * 3 + 2]);
    rec[pos] = r;
}

// ---------------- weight fp32->bf16 ----------------

struct CvtEnt { const float* s; u16* d; int n; };
struct CvtTab { CvtEnt e[14]; };
__global__ void k_cvt_w(CvtTab tab) {
    CvtEnt E = tab.e[blockIdx.x];
    for (int i = threadIdx.x; i < E.n; i += blockDim.x) E.d[i] = f2us(E.s[i]);
}

// ---------------- fused QKVS GEMM ----------------
// A [NPAD,128] (fp32 if A32 else bf16); W = [Wq|Wk|Wv|Ws] 512x128 bf16.
// Out row (stride 512 u16): [q 0..127 | kv interleaved 128..383 | s 384..511]
// where kv[4p+0..3] = {k[2p],k[2p+1],v[2p],v[2p+1]}.
// Block = 4 waves, 64 rows. MFMA 16x16x32 (m89 layouts).

template <bool A32>
__global__ __launch_bounds__(256) void k_qkvs(const void* __restrict__ Ain,
                                              const u16* __restrict__ W,
                                              u16* __restrict__ QKVS) {
    __shared__ u16 tile[64 * 264];   // stride 264 u16 = 528 B (16B-aligned rows)
    int tid = threadIdx.x;
    int l = tid & 63, w = tid >> 6, m = l & 15, kb = l >> 4;
    int r0 = blockIdx.x * 64;
    int ar = r0 + w * 16 + m;

    short8 a0, a1, a2, a3;
    if (A32) {
        const float* ap = (const float*)Ain + (size_t)ar * 128;
        bool ok = ar < NN;
        short8* dsts[4] = {&a0, &a1, &a2, &a3};
#pragma unroll
        for (int i = 0; i < 4; ++i) {
            short8 r;
            if (ok) {
                const float* p = ap + (kb + i * 4) * 8;
                float4 f0 = *(const float4*)p;
                float4 f1 = *(const float4*)(p + 4);
                r[0]=(short)f2us(f0.x); r[1]=(short)f2us(f0.y); r[2]=(short)f2us(f0.z); r[3]=(short)f2us(f0.w);
                r[4]=(short)f2us(f1.x); r[5]=(short)f2us(f1.y); r[6]=(short)f2us(f1.z); r[7]=(short)f2us(f1.w);
            } else {
#pragma unroll
                for (int j = 0; j < 8; ++j) r[j] = 0;
            }
            *dsts[i] = r;
        }
    } else {
        const short8* ap = (const short8*)((const u16*)Ain + (size_t)ar * 128);
        a0 = ap[kb]; a1 = ap[kb + 4]; a2 = ap[kb + 8]; a3 = ap[kb + 12];
    }

    auto mfma_tile = [&](int wrow) -> float4v {
        const short8* wr = (const short8*)(W + (size_t)(wrow + m) * 128);
        short8 b0 = wr[kb], b1 = wr[kb + 4], b2 = wr[kb + 8], b3 = wr[kb + 12];
        float4v acc = {0.f, 0.f, 0.f, 0.f};
        acc = __builtin_amdgcn_mfma_f32_16x16x32_bf16(a0, b0, acc, 0, 0, 0);
        acc = __builtin_amdgcn_mfma_f32_16x16x32_bf16(a1, b1, acc, 0, 0, 0);
        acc = __builtin_amdgcn_mfma_f32_16x16x32_bf16(a2, b2, acc, 0, 0, 0);
        acc = __builtin_amdgcn_mfma_f32_16x16x32_bf16(a3, b3, acc, 0, 0, 0);
        return acc;
    };
    int lrow = w * 16 + kb * 4;

    // ---- q (W rows 0..127) ----
#pragma unroll
    for (int tt = 0; tt < 8; ++tt) {
        float4v acc = mfma_tile(tt * 16);
#pragma unroll
        for (int r = 0; r < 4; ++r) tile[(lrow + r) * 264 + tt * 16 + m] = f2us(acc[r]);
    }
    __syncthreads();
#pragma unroll
    for (int it = 0; it < 4; ++it) {
        int q = (it * 256 + tid) * 8;
        int row = q >> 7, col = q & 127;
        uint4 pk = *(const uint4*)&tile[row * 264 + col];
        *(uint4*)(QKVS + (size_t)(r0 + row) * 512 + col) = pk;
    }
    __syncthreads();
    // ---- k (rows 128..255) + v (rows 256..383), interleaved staging ----
#pragma unroll
    for (int tt = 0; tt < 8; ++tt) {
        float4v acc = mfma_tile(128 + tt * 16);
        int c = tt * 32 + 4 * (m >> 1) + (m & 1);
#pragma unroll
        for (int r = 0; r < 4; ++r) tile[(lrow + r) * 264 + c] = f2us(acc[r]);
    }
#pragma unroll
    for (int tt = 0; tt < 8; ++tt) {
        float4v acc = mfma_tile(256 + tt * 16);
        int c = tt * 32 + 4 * (m >> 1) + (m & 1) + 2;
#pragma unroll
        for (int r = 0; r < 4; ++r) tile[(lrow + r) * 264 + c] = f2us(acc[r]);
    }
    __syncthreads();
#pragma unroll
    for (int it = 0; it < 8; ++it) {
        int q = (it * 256 + tid) * 8;
        int row = q >> 8, col = q & 255;
        uint4 pk = *(const uint4*)&tile[row * 264 + col];
        *(uint4*)(QKVS + (size_t)(r0 + row) * 512 + 128 + col) = pk;
    }
    __syncthreads();
    // ---- s (rows 384..511) ----
#pragma unroll
    for (int tt = 0; tt < 8; ++tt) {
        float4v acc = mfma_tile(384 + tt * 16);
#pragma unroll
        for (int r = 0; r < 4; ++r) tile[(lrow + r) * 264 + tt * 16 + m] = f2us(acc[r]);
    }
    __syncthreads();
#pragma unroll
    for (int it = 0; it < 4; ++it) {
        int q = (it * 256 + tid) * 8;
        int row = q >> 7, col = q & 127;
        uint4 pk = *(const uint4*)&tile[row * 264 + col];
        *(uint4*)(QKVS + (size_t)(r0 + row) * 512 + 384 + col) = pk;
    }
}

// ---------------- fused 2-layer MLP ----------------
// out = gelu(gelu(A@W1^T + b1)@W2^T + b2) [+ A if RES]; W2 = Wb+16384 (contig).
// T1 staged bf16 in LDS, re-read as A-frags (ds_read_b128).

template <int TPG2, bool RES, bool F32OUT>
__global__ __launch_bounds__(256) void k_mlp(const u16* __restrict__ Ain,
                                             const u16* __restrict__ Wb,
                                             const float* __restrict__ bias1,
                                             const float* __restrict__ bias2,
                                             void* __restrict__ outp) {
    __shared__ u16 t1[64 * 136];
    __shared__ u16 ct[64 * 136];
    int tid = threadIdx.x;
    int l = tid & 63, w = tid >> 6, m = l & 15, kb = l >> 4;
    int r0 = blockIdx.x * 64;
    const short8* arow = (const short8*)(Ain + (size_t)(r0 + w * 16 + m) * 128);
    short8 a0 = arow[kb], a1 = arow[kb + 4], a2 = arow[kb + 8], a3 = arow[kb + 12];
    const u16* W2 = Wb + 16384;
    int lrow = w * 16 + kb * 4;

#pragma unroll
    for (int tt = 0; tt < 8; ++tt) {
        const short8* wr = (const short8*)(Wb + (size_t)(tt * 16 + m) * 128);
        short8 b0 = wr[kb], b1 = wr[kb + 4], b2 = wr[kb + 8], b3 = wr[kb + 12];
        float4v acc = {0.f, 0.f, 0.f, 0.f};
        acc = __builtin_amdgcn_mfma_f32_16x16x32_bf16(a0, b0, acc, 0, 0, 0);
        acc = __builtin_amdgcn_mfma_f32_16x16x32_bf16(a1, b1, acc, 0, 0, 0);
        acc = __builtin_amdgcn_mfma_f32_16x16x32_bf16(a2, b2, acc, 0, 0, 0);
        acc = __builtin_amdgcn_mfma_f32_16x16x32_bf16(a3, b3, acc, 0, 0, 0);
        float bv = bias1[tt * 16 + m];
#pragma unroll
        for (int r = 0; r < 4; ++r)
            t1[(lrow + r) * 136 + tt * 16 + m] = f2us(gelu_f(acc[r] + bv));
    }
    __syncthreads();
    const u16* t1r = t1 + (w * 16 + m) * 136;
    short8 c0 = *(const short8*)(t1r + (kb + 0) * 8);
    short8 c1 = *(const short8*)(t1r + (kb + 4) * 8);
    short8 c2 = *(const short8*)(t1r + (kb + 8) * 8);
    short8 c3 = *(const short8*)(t1r + (kb + 12) * 8);

#pragma unroll
    for (int tt = 0; tt < TPG2; ++tt) {
        const short8* wr = (const short8*)(W2 + (size_t)(tt * 16 + m) * 128);
        short8 b0 = wr[kb], b1 = wr[kb + 4], b2 = wr[kb + 8], b3 = wr[kb + 12];
        float4v acc = {0.f, 0.f, 0.f, 0.f};
        acc = __builtin_amdgcn_mfma_f32_16x16x32_bf16(c0, b0, acc, 0, 0, 0);
        acc = __builtin_amdgcn_mfma_f32_16x16x32_bf16(c1, b1, acc, 0, 0, 0);
        acc = __builtin_amdgcn_mfma_f32_16x16x32_bf16(c2, b2, acc, 0, 0, 0);
        acc = __builtin_amdgcn_mfma_f32_16x16x32_bf16(c3, b3, acc, 0, 0, 0);
        float bv = bias2[tt * 16 + m];
#pragma unroll
        for (int r = 0; r < 4; ++r)
            ct[(lrow + r) * 136 + tt * 16 + m] = f2us(gelu_f(acc[r] + bv));
    }
    __syncthreads();
    constexpr int CW = TPG2 * 16;
#pragma unroll
    for (int it = 0; it < (64 * CW) / 2048; ++it) {
        int q = (it * 256 + tid) * 8;
        int row = q / CW, col = q % CW;
        int grow = r0 + row;
        uint4 pk = *(const uint4*)&ct[row * 136 + col];
        const u16* pv = (const u16*)&pk;
        if (F32OUT) {
            if (grow < NN) {
                float* po = (float*)outp + (size_t)grow * CW + col;
                float4 o0 = {us2f(pv[0]), us2f(pv[1]), us2f(pv[2]), us2f(pv[3])};
                float4 o1 = {us2f(pv[4]), us2f(pv[5]), us2f(pv[6]), us2f(pv[7])};
                *(float4*)po = o0;
                *(float4*)(po + 4) = o1;
            }
        } else {
            uint4 o = pk;
            if (RES) {
                uint4 rk = *(const uint4*)(Ain + (size_t)grow * 128 + col);
                const u16* pr = (const u16*)&rk;
                u16* po = (u16*)&o;
#pragma unroll
                for (int j = 0; j < 8; ++j) po[j] = f2us(us2f(pv[j]) + us2f(pr[j]));
            }
            *(uint4*)((u16*)outp + (size_t)grow * 128 + col) = o;
        }
    }
}

// ---------------- TransformerConv aggregation ----------------
// 1 wave/node, 2 cols/lane; no-max softmax (exp clamped at 80); kv dwordx2 gather.

__global__ __launch_bounds__(256) void k_conv(const int* __restrict__ rowstart,
                                              const int4* __restrict__ rec,
                                              const u16* __restrict__ qkvs,
                                              const float* __restrict__ We,
                                              u16* __restrict__ out) {
    int n = blockIdx.x * 4 + (threadIdx.x >> 6);
    int l = threadIdx.x & 63;
    int c0 = (l >> 4) * 32 + (l & 15) * 2;
    const u16* qrow = qkvs + (size_t)n * 512;
    u32 qu = *(const u32*)(qrow + c0);
    float q0 = blo(qu), q1 = bhi(qu);
    float we00 = We[c0 * 3 + 0], we01 = We[c0 * 3 + 1], we02 = We[c0 * 3 + 2];
    float we10 = We[c0 * 3 + 3], we11 = We[c0 * 3 + 4], we12 = We[c0 * 3 + 5];
    int e0 = rowstart[n], e1 = rowstart[n + 1];
    float ss = 0.f, o0 = 0.f, o1 = 0.f;

    auto edge = [&](int4 r, uint2 kv) {
        float ea0 = __int_as_float(r.y), ea1 = __int_as_float(r.z), ea2 = __int_as_float(r.w);
        float ev0 = fmaf(ea2, we02, fmaf(ea1, we01, ea0 * we00));
        float ev1 = fmaf(ea2, we12, fmaf(ea1, we11, ea0 * we10));
        float k0 = blo(kv.x) + ev0, k1 = bhi(kv.x) + ev1;
        float v0 = blo(kv.y) + ev0, v1 = bhi(kv.y) + ev1;
        float part = fmaf(q1, k1, q0 * k0);
        part += __shfl_xor(part, 8);
        part += __shfl_xor(part, 4);
        part += __shfl_xor(part, 2);
        part += __shfl_xor(part, 1);
        float p = __expf(fminf(part * 0.17677669529663687f, 80.f));
        o0 = fmaf(p, v0, o0);
        o1 = fmaf(p, v1, o1);
        ss += p;
    };

    int e = e0;
    if ((e1 - e0) & 1) {
        int4 r = rec[e];
        uint2 kv = *(const uint2*)(qkvs + (size_t)r.x * 512 + 128 + c0 * 2);
        edge(r, kv);
        ++e;
    }
    for (; e < e1; e += 2) {
        int4 ra = rec[e], rb = rec[e + 1];
        uint2 kva = *(const uint2*)(qkvs + (size_t)ra.x * 512 + 128 + c0 * 2);
        uint2 kvb = *(const uint2*)(qkvs + (size_t)rb.x * 512 + 128 + c0 * 2);
        edge(ra, kva);
        edge(rb, kvb);
    }
    float inv = __builtin_amdgcn_rcpf(fmaxf(ss, 1e-16f));
    u32 su = *(const u32*)(qrow + 384 + c0);
    float r0v = fmaf(o0, inv, blo(su));
    float r1v = fmaf(o1, inv, bhi(su));
    u32 ou = (u32)f2us(r0v) | ((u32)f2us(r1v) << 16);
    *(u32*)(out + (size_t)n * 128 + c0) = ou;
}

// ---------------- launcher ----------------

extern "C" void kernel_launch(void* const* d_in, const int* in_sizes, int n_in,
                              void* d_out, int out_size, void* d_ws, size_t ws_size,
                              hipStream_t stream) {
    const float* x = (const float*)d_in[0];
    const int* ei = (const int*)d_in[1];
    const float* eattr = (const float*)d_in[2];
    const float* Wq1 = (const float*)d_in[3];
    const float* Wk1 = (const float*)d_in[4];
    const float* Wv1 = (const float*)d_in[5];
    const float* We1 = (const float*)d_in[6];
    const float* Ws1 = (const float*)d_in[7];
    const float* M1a = (const float*)d_in[8];
    const float* b1a = (const float*)d_in[9];
    const float* M1b = (const float*)d_in[10];
    const float* b1b = (const float*)d_in[11];
    const float* Wq2 = (const float*)d_in[12];
    const float* Wk2 = (const float*)d_in[13];
    const float* Wv2 = (const float*)d_in[14];
    const float* We2 = (const float*)d_in[15];
    const float* Ws2 = (const float*)d_in[16];
    const float* M2a = (const float*)d_in[17];
    const float* b2a = (const float*)d_in[18];
    const float* M2b = (const float*)d_in[19];
    const float* b2b = (const float*)d_in[20];
    const float* Wf1 = (const float*)d_in[21];
    const float* bf1 = (const float*)d_in[22];
    const float* Wf2 = (const float*)d_in[23];
    const float* bf2 = (const float*)d_in[24];

    char* ws = (char*)d_ws;
    size_t off = 0;
    auto alloc = [&](size_t bytes) -> void* {
        void* p = ws + off;
        off = (off + bytes + 255) & ~(size_t)255;
        return p;
    };
    int* deg = (int*)alloc((size_t)NN * 4);
    int* rowstart = (int*)alloc((size_t)(NN + 1) * 4);
    int* cursor = (int*)alloc((size_t)NN * 4);
    int4* rec = (int4*)alloc((size_t)NE * 16);
    u16* QKVS = (u16*)alloc((size_t)NPAD * 512 * 2);
    u16* Ha = (u16*)alloc((size_t)NPAD * 128 * 2);
    u16* Hb = (u16*)alloc((size_t)NPAD * 128 * 2);
    u16* Hc = (u16*)alloc((size_t)NPAD * 128 * 2);
    // weight order: [Wq1 Wk1 Wv1 Ws1][Wq2 Wk2 Wv2 Ws2][M1a M1b][M2a M2b][Wf1 Wf2]
    // (alloc is 256B-aligned and sizes are multiples of 256B -> contiguous groups)
    u16* WB[14];
    const int wsz[14] = {16384, 16384, 16384, 16384, 16384, 16384, 16384,
                         16384, 16384, 16384, 16384, 16384, 16384, 8192};
    for (int i = 0; i < 14; ++i) WB[i] = (u16*)alloc((size_t)wsz[i] * 2);

    const int* srcv = ei;
    const int* dstv = ei + NE;

    // CSR build (shared by both conv layers)
    k_zero<<<(NN + 255) / 256, 256, 0, stream>>>(deg, NN);
    k_hist<<<(NE + 255) / 256, 256, 0, stream>>>(dstv, deg);
    k_scan<<<1, 1024, 0, stream>>>(deg, rowstart, cursor);
    k_scatter<<<(NE + 255) / 256, 256, 0, stream>>>(srcv, dstv, eattr, cursor, rec);

    CvtTab tab;
    const float* wsrc[14] = {Wq1, Wk1, Wv1, Ws1, Wq2, Wk2, Wv2, Ws2,
                             M1a, M1b, M2a, M2b, Wf1, Wf2};
    for (int i = 0; i < 14; ++i) { tab.e[i].s = wsrc[i]; tab.e[i].d = WB[i]; tab.e[i].n = wsz[i]; }
    k_cvt_w<<<14, 256, 0, stream>>>(tab);

    dim3 blk(256);
    dim3 grd(NPAD / 64);   // 782
    dim3 gconv(NN / 4);    // 12500

    // ----- layer 1 -----
    k_qkvs<true><<<grd, blk, 0, stream>>>(x, WB[0], QKVS);
    k_conv<<<gconv, blk, 0, stream>>>(rowstart, rec, QKVS, We1, Ha);                 // H1 = Ha
    k_mlp<8, true, false><<<grd, blk, 0, stream>>>(Ha, WB[8], b1a, b1b, Hc);         // H2 = Hc

    // ----- layer 2 -----
    k_qkvs<false><<<grd, blk, 0, stream>>>(Hc, WB[4], QKVS);
    k_conv<<<gconv, blk, 0, stream>>>(rowstart, rec, QKVS, We2, Ha);                 // H3 = Ha
    k_mlp<8, true, false><<<grd, blk, 0, stream>>>(Ha, WB[10], b2a, b2b, Hb);        // H4 = Hb

    // ----- final MLP -----
    k_mlp<4, false, true><<<grd, blk, 0, stream>>>(Hb, WB[12], bf1, bf2, d_out);
}

// Round 6
// 589.803 us; speedup vs baseline: 2.6427x; 1.0717x over previous
//
#include <hip/hip_runtime.h>
#include <hip/hip_bf16.h>
#include <math.h>

// Problem constants (fixed by the reference)
#define NN 50000
#define NE 800000
#define NPAD 50048   // 782 * 64 — tail-free GEMM tiles
#define NB_SCAN 196  // ceil(NN/256)

typedef unsigned short u16;
typedef unsigned int u32;
typedef __attribute__((ext_vector_type(8))) short short8;   // 8 bf16 (MFMA A/B frag)
typedef __attribute__((ext_vector_type(4))) float float4v;  // MFMA C/D frag

__device__ __forceinline__ float us2f(u16 u) { return __uint_as_float(((unsigned)u) << 16); }
__device__ __forceinline__ float blo(u32 u) { return __uint_as_float(u << 16); }
__device__ __forceinline__ float bhi(u32 u) { return __uint_as_float(u & 0xffff0000u); }
__device__ __forceinline__ u16 f2us(float f) {   // fp32 -> bf16 RNE
    unsigned x = __float_as_uint(f);
    return (u16)((x + 0x7FFFu + ((x >> 16) & 1u)) >> 16);
}
// tanh-gelu via sigmoid identity: 0.5*(1+tanh(u)) = sigmoid(2u)
__device__ __forceinline__ float gelu_f(float x) {
    float p = x * x;
    float t = x * fmaf(p, 0.0713548162726f, 1.5957691216057308f);  // 2u
    float e = __expf(-t);
    return x * __builtin_amdgcn_rcpf(1.0f + e);
}

// ---------------- CSR build ----------------

__global__ void k_hist(const int* __restrict__ dstv, int* __restrict__ deg) {
    int e = blockIdx.x * blockDim.x + threadIdx.x;
    if (e < NE) atomicAdd(&deg[dstv[e]], 1);
}

// phase 1: per-block exclusive scan of deg -> rowstart (block-local), block sums -> bsum
__global__ __launch_bounds__(256) void k_scan1(const int* __restrict__ deg,
                                               int* __restrict__ rowstart,
                                               int* __restrict__ bsum) {
    __shared__ int wtot[4];
    int i = blockIdx.x * 256 + threadIdx.x;
    int lane = threadIdx.x & 63, w = threadIdx.x >> 6;
    int v = (i < NN) ? deg[i] : 0;
    int incl = v;
#pragma unroll
    for (int d = 1; d < 64; d <<= 1) {
        int tv = __shfl_up(incl, d);
        if (lane >= d) incl += tv;
    }
    if (lane == 63) wtot[w] = incl;
    __syncthreads();
    if (threadIdx.x == 0) {
        int s = 0;
#pragma unroll
        for (int j = 0; j < 4; ++j) { int t = wtot[j]; wtot[j] = s; s += t; }
        bsum[blockIdx.x] = s;
    }
    __syncthreads();
    if (i < NN) rowstart[i] = incl - v + wtot[w];
}

// phase 2: exclusive scan of the NB_SCAN block sums (single 256-thread block)
__global__ __launch_bounds__(256) void k_scan2(int* __restrict__ bsum) {
    __shared__ int wtot[4];
    int t = threadIdx.x;
    int lane = t & 63, w = t >> 6;
    int v = (t < NB_SCAN) ? bsum[t] : 0;
    int incl = v;
#pragma unroll
    for (int d = 1; d < 64; d <<= 1) {
        int tv = __shfl_up(incl, d);
        if (lane >= d) incl += tv;
    }
    if (lane == 63) wtot[w] = incl;
    __syncthreads();
    if (t == 0) {
        int s = 0;
#pragma unroll
        for (int j = 0; j < 4; ++j) { int tt = wtot[j]; wtot[j] = s; s += tt; }
    }
    __syncthreads();
    if (t < NB_SCAN) bsum[t] = incl - v + wtot[w];
}

// phase 3: add block offsets; init cursor; rowstart[NN]=NE
__global__ void k_scan3(const int* __restrict__ bsum, int* __restrict__ rowstart,
                        int* __restrict__ cursor) {
    int i = blockIdx.x * 256 + threadIdx.x;
    if (i < NN) {
        int v = rowstart[i] + bsum[blockIdx.x];
        rowstart[i] = v;
        cursor[i] = v;
    }
    if (i == 0) rowstart[NN] = NE;
}

__global__ void k_scatter(const int* __restrict__ srcv, const int* __restrict__ dstv,
                          const float* __restrict__ eattr, int* __restrict__ cursor,
                          int4* __restrict__ rec) {
    int e = blockIdx.x * blockDim.x + threadIdx.x;
    if (e >= NE) return;
    int dst = dstv[e];
    int pos = atomicAdd(&cursor[dst], 1);
    int4 r;
    r.x = srcv[e];
    r.y = __float_as_int(eattr[e * 3 + 0]);
    r.z = __float_as_int(eattr[e * 3 + 1]);
    r.w = __float_as_int(eattr[e * 3 + 2]);
    rec[pos] = r;
}

// ---------------- weight fp32->bf16 (112 blocks: entry = b>>3, 1/8 chunk each) ----------------

struct CvtEnt { const float* s; u16* d; int n; };
struct CvtTab { CvtEnt e[14]; };
__global__ void k_cvt_w(CvtTab tab) {
    CvtEnt E = tab.e[blockIdx.x >> 3];
    int chunk = blockIdx.x & 7;
    int per = E.n >> 3;
    int lo = chunk * per, hi = lo + per;
    for (int i = lo + threadIdx.x; i < hi; i += blockDim.x) E.d[i] = f2us(E.s[i]);
}

// ---------------- fused QKVS GEMM ----------------
// A [NPAD,128] (fp32 if A32 else bf16); W = [Wq|Wk|Wv|Ws] 512x128 bf16.
// Out row (stride 512 u16): [q 0..127 | kv interleaved 128..383 | s 384..511]
// where kv[4p+0..3] = {k[2p],k[2p+1],v[2p],v[2p+1]}.

template <bool A32>
__global__ __launch_bounds__(256) void k_qkvs(const void* __restrict__ Ain,
                                              const u16* __restrict__ W,
                                              u16* __restrict__ QKVS) {
    __shared__ u16 tile[64 * 264];
    int tid = threadIdx.x;
    int l = tid & 63, w = tid >> 6, m = l & 15, kb = l >> 4;
    int r0 = blockIdx.x * 64;
    int ar = r0 + w * 16 + m;

    short8 a0, a1, a2, a3;
    if (A32) {
        const float* ap = (const float*)Ain + (size_t)ar * 128;
        bool ok = ar < NN;
        short8* dsts[4] = {&a0, &a1, &a2, &a3};
#pragma unroll
        for (int i = 0; i < 4; ++i) {
            short8 r;
            if (ok) {
                const float* p = ap + (kb + i * 4) * 8;
                float4 f0 = *(const float4*)p;
                float4 f1 = *(const float4*)(p + 4);
                r[0]=(short)f2us(f0.x); r[1]=(short)f2us(f0.y); r[2]=(short)f2us(f0.z); r[3]=(short)f2us(f0.w);
                r[4]=(short)f2us(f1.x); r[5]=(short)f2us(f1.y); r[6]=(short)f2us(f1.z); r[7]=(short)f2us(f1.w);
            } else {
#pragma unroll
                for (int j = 0; j < 8; ++j) r[j] = 0;
            }
            *dsts[i] = r;
        }
    } else {
        const short8* ap = (const short8*)((const u16*)Ain + (size_t)ar * 128);
        a0 = ap[kb]; a1 = ap[kb + 4]; a2 = ap[kb + 8]; a3 = ap[kb + 12];
    }

    auto mfma_tile = [&](int wrow) -> float4v {
        const short8* wr = (const short8*)(W + (size_t)(wrow + m) * 128);
        short8 b0 = wr[kb], b1 = wr[kb + 4], b2 = wr[kb + 8], b3 = wr[kb + 12];
        float4v acc = {0.f, 0.f, 0.f, 0.f};
        acc = __builtin_amdgcn_mfma_f32_16x16x32_bf16(a0, b0, acc, 0, 0, 0);
        acc = __builtin_amdgcn_mfma_f32_16x16x32_bf16(a1, b1, acc, 0, 0, 0);
        acc = __builtin_amdgcn_mfma_f32_16x16x32_bf16(a2, b2, acc, 0, 0, 0);
        acc = __builtin_amdgcn_mfma_f32_16x16x32_bf16(a3, b3, acc, 0, 0, 0);
        return acc;
    };
    int lrow = w * 16 + kb * 4;

    // ---- q ----
#pragma unroll
    for (int tt = 0; tt < 8; ++tt) {
        float4v acc = mfma_tile(tt * 16);
#pragma unroll
        for (int r = 0; r < 4; ++r) tile[(lrow + r) * 264 + tt * 16 + m] = f2us(acc[r]);
    }
    __syncthreads();
#pragma unroll
    for (int it = 0; it < 4; ++it) {
        int q = (it * 256 + tid) * 8;
        int row = q >> 7, col = q & 127;
        uint4 pk = *(const uint4*)&tile[row * 264 + col];
        *(uint4*)(QKVS + (size_t)(r0 + row) * 512 + col) = pk;
    }
    __syncthreads();
    // ---- k + v interleaved ----
#pragma unroll
    for (int tt = 0; tt < 8; ++tt) {
        float4v acc = mfma_tile(128 + tt * 16);
        int c = tt * 32 + 4 * (m >> 1) + (m & 1);
#pragma unroll
        for (int r = 0; r < 4; ++r) tile[(lrow + r) * 264 + c] = f2us(acc[r]);
    }
#pragma unroll
    for (int tt = 0; tt < 8; ++tt) {
        float4v acc = mfma_tile(256 + tt * 16);
        int c = tt * 32 + 4 * (m >> 1) + (m & 1) + 2;
#pragma unroll
        for (int r = 0; r < 4; ++r) tile[(lrow + r) * 264 + c] = f2us(acc[r]);
    }
    __syncthreads();
#pragma unroll
    for (int it = 0; it < 8; ++it) {
        int q = (it * 256 + tid) * 8;
        int row = q >> 8, col = q & 255;
        uint4 pk = *(const uint4*)&tile[row * 264 + col];
        *(uint4*)(QKVS + (size_t)(r0 + row) * 512 + 128 + col) = pk;
    }
    __syncthreads();
    // ---- s ----
#pragma unroll
    for (int tt = 0; tt < 8; ++tt) {
        float4v acc = mfma_tile(384 + tt * 16);
#pragma unroll
        for (int r = 0; r < 4; ++r) tile[(lrow + r) * 264 + tt * 16 + m] = f2us(acc[r]);
    }
    __syncthreads();
#pragma unroll
    for (int it = 0; it < 4; ++it) {
        int q = (it * 256 + tid) * 8;
        int row = q >> 7, col = q & 127;
        uint4 pk = *(const uint4*)&tile[row * 264 + col];
        *(uint4*)(QKVS + (size_t)(r0 + row) * 512 + 384 + col) = pk;
    }
}

// ---------------- fused 2-layer MLP ----------------

template <int TPG2, bool RES, bool F32OUT>
__global__ __launch_bounds__(256) void k_mlp(const u16* __restrict__ Ain,
                                             const u16* __restrict__ Wb,
                                             const float* __restrict__ bias1,
                                             const float* __restrict__ bias2,
                                             void* __restrict__ outp) {
    __shared__ u16 t1[64 * 136];
    __shared__ u16 ct[64 * 136];
    int tid = threadIdx.x;
    int l = tid & 63, w = tid >> 6, m = l & 15, kb = l >> 4;
    int r0 = blockIdx.x * 64;
    const short8* arow = (const short8*)(Ain + (size_t)(r0 + w * 16 + m) * 128);
    short8 a0 = arow[kb], a1 = arow[kb + 4], a2 = arow[kb + 8], a3 = arow[kb + 12];
    const u16* W2 = Wb + 16384;
    int lrow = w * 16 + kb * 4;

#pragma unroll
    for (int tt = 0; tt < 8; ++tt) {
        const short8* wr = (const short8*)(Wb + (size_t)(tt * 16 + m) * 128);
        short8 b0 = wr[kb], b1 = wr[kb + 4], b2 = wr[kb + 8], b3 = wr[kb + 12];
        float4v acc = {0.f, 0.f, 0.f, 0.f};
        acc = __builtin_amdgcn_mfma_f32_16x16x32_bf16(a0, b0, acc, 0, 0, 0);
        acc = __builtin_amdgcn_mfma_f32_16x16x32_bf16(a1, b1, acc, 0, 0, 0);
        acc = __builtin_amdgcn_mfma_f32_16x16x32_bf16(a2, b2, acc, 0, 0, 0);
        acc = __builtin_amdgcn_mfma_f32_16x16x32_bf16(a3, b3, acc, 0, 0, 0);
        float bv = bias1[tt * 16 + m];
#pragma unroll
        for (int r = 0; r < 4; ++r)
            t1[(lrow + r) * 136 + tt * 16 + m] = f2us(gelu_f(acc[r] + bv));
    }
    __syncthreads();
    const u16* t1r = t1 + (w * 16 + m) * 136;
    short8 c0 = *(const short8*)(t1r + (kb + 0) * 8);
    short8 c1 = *(const short8*)(t1r + (kb + 4) * 8);
    short8 c2 = *(const short8*)(t1r + (kb + 8) * 8);
    short8 c3 = *(const short8*)(t1r + (kb + 12) * 8);

#pragma unroll
    for (int tt = 0; tt < TPG2; ++tt) {
        const short8* wr = (const short8*)(W2 + (size_t)(tt * 16 + m) * 128);
        short8 b0 = wr[kb], b1 = wr[kb + 4], b2 = wr[kb + 8], b3 = wr[kb + 12];
        float4v acc = {0.f, 0.f, 0.f, 0.f};
        acc = __builtin_amdgcn_mfma_f32_16x16x32_bf16(c0, b0, acc, 0, 0, 0);
        acc = __builtin_amdgcn_mfma_f32_16x16x32_bf16(c1, b1, acc, 0, 0, 0);
        acc = __builtin_amdgcn_mfma_f32_16x16x32_bf16(c2, b2, acc, 0, 0, 0);
        acc = __builtin_amdgcn_mfma_f32_16x16x32_bf16(c3, b3, acc, 0, 0, 0);
        float bv = bias2[tt * 16 + m];
#pragma unroll
        for (int r = 0; r < 4; ++r)
            ct[(lrow + r) * 136 + tt * 16 + m] = f2us(gelu_f(acc[r] + bv));
    }
    __syncthreads();
    constexpr int CW = TPG2 * 16;
#pragma unroll
    for (int it = 0; it < (64 * CW) / 2048; ++it) {
        int q = (it * 256 + tid) * 8;
        int row = q / CW, col = q % CW;
        int grow = r0 + row;
        uint4 pk = *(const uint4*)&ct[row * 136 + col];
        const u16* pv = (const u16*)&pk;
        if (F32OUT) {
            if (grow < NN) {
                float* po = (float*)outp + (size_t)grow * CW + col;
                float4 o0 = {us2f(pv[0]), us2f(pv[1]), us2f(pv[2]), us2f(pv[3])};
                float4 o1 = {us2f(pv[4]), us2f(pv[5]), us2f(pv[6]), us2f(pv[7])};
                *(float4*)po = o0;
                *(float4*)(po + 4) = o1;
            }
        } else {
            uint4 o = pk;
            if (RES) {
                uint4 rk = *(const uint4*)(Ain + (size_t)grow * 128 + col);
                const u16* pr = (const u16*)&rk;
                u16* po = (u16*)&o;
#pragma unroll
                for (int j = 0; j < 8; ++j) po[j] = f2us(us2f(pv[j]) + us2f(pr[j]));
            }
            *(uint4*)((u16*)outp + (size_t)grow * 128 + col) = o;
        }
    }
}

// ---------------- TransformerConv aggregation: 2 waves/node, additive partials ----------------
// Block = 256 threads = 4 waves = 2 nodes (waves 0,1 -> node A; 2,3 -> node B).
// Wave takes edges e0+half, e0+half+2, ... ; partials (o0,o1,ss) combined in LDS.
// No-max softmax: p = exp(min(alpha,80)); partial sums are exactly additive.

__global__ __launch_bounds__(256) void k_conv(const int* __restrict__ rowstart,
                                              const int4* __restrict__ rec,
                                              const u16* __restrict__ qkvs,
                                              const float* __restrict__ We,
                                              u16* __restrict__ out) {
    __shared__ float2 lo[4][64];
    __shared__ float lss[4][64];
    int w = threadIdx.x >> 6;
    int l = threadIdx.x & 63;
    int n = blockIdx.x * 2 + (w >> 1);
    int half = w & 1;
    int c0 = (l >> 4) * 32 + (l & 15) * 2;
    const u16* qrow = qkvs + (size_t)n * 512;
    u32 qu = *(const u32*)(qrow + c0);
    float q0 = blo(qu), q1 = bhi(qu);
    float we00 = We[c0 * 3 + 0], we01 = We[c0 * 3 + 1], we02 = We[c0 * 3 + 2];
    float we10 = We[c0 * 3 + 3], we11 = We[c0 * 3 + 4], we12 = We[c0 * 3 + 5];
    int e0 = rowstart[n], e1 = rowstart[n + 1];
    float ss = 0.f, o0 = 0.f, o1 = 0.f;

    auto edge = [&](int4 r, uint2 kv) {
        float ea0 = __int_as_float(r.y), ea1 = __int_as_float(r.z), ea2 = __int_as_float(r.w);
        float ev0 = fmaf(ea2, we02, fmaf(ea1, we01, ea0 * we00));
        float ev1 = fmaf(ea2, we12, fmaf(ea1, we11, ea0 * we10));
        float k0 = blo(kv.x) + ev0, k1 = bhi(kv.x) + ev1;
        float v0 = blo(kv.y) + ev0, v1 = bhi(kv.y) + ev1;
        float part = fmaf(q1, k1, q0 * k0);
        part += __shfl_xor(part, 8);
        part += __shfl_xor(part, 4);
        part += __shfl_xor(part, 2);
        part += __shfl_xor(part, 1);
        float p = __expf(fminf(part * 0.17677669529663687f, 80.f));
        o0 = fmaf(p, v0, o0);
        o1 = fmaf(p, v1, o1);
        ss += p;
    };

    int e = e0 + half;
    int ne = e1 - e;                 // remaining stride-2 count = ceil(ne/2)
    int cnt = (ne > 0) ? ((ne + 1) >> 1) : 0;
    if (cnt & 1) {
        int4 r = rec[e];
        uint2 kv = *(const uint2*)(qkvs + (size_t)r.x * 512 + 128 + c0 * 2);
        edge(r, kv);
        e += 2;
    }
    for (int i = 0; i < (cnt >> 1); ++i, e += 4) {
        int4 ra = rec[e], rb = rec[e + 2];
        uint2 kva = *(const uint2*)(qkvs + (size_t)ra.x * 512 + 128 + c0 * 2);
        uint2 kvb = *(const uint2*)(qkvs + (size_t)rb.x * 512 + 128 + c0 * 2);
        edge(ra, kva);
        edge(rb, kvb);
    }

    lo[w][l] = make_float2(o0, o1);
    lss[w][l] = ss;
    __syncthreads();
    if (half == 0) {
        float2 p = lo[w + 1][l];
        float s2 = ss + lss[w + 1][l];
        float t0 = o0 + p.x, t1 = o1 + p.y;
        float inv = __builtin_amdgcn_rcpf(fmaxf(s2, 1e-16f));
        u32 su = *(const u32*)(qrow + 384 + c0);
        float r0v = fmaf(t0, inv, blo(su));
        float r1v = fmaf(t1, inv, bhi(su));
        u32 ou = (u32)f2us(r0v) | ((u32)f2us(r1v) << 16);
        *(u32*)(out + (size_t)n * 128 + c0) = ou;
    }
}

// ---------------- launcher ----------------

extern "C" void kernel_launch(void* const* d_in, const int* in_sizes, int n_in,
                              void* d_out, int out_size, void* d_ws, size_t ws_size,
                              hipStream_t stream) {
    const float* x = (const float*)d_in[0];
    const int* ei = (const int*)d_in[1];
    const float* eattr = (const float*)d_in[2];
    const float* Wq1 = (const float*)d_in[3];
    const float* Wk1 = (const float*)d_in[4];
    const float* Wv1 = (const float*)d_in[5];
    const float* We1 = (const float*)d_in[6];
    const float* Ws1 = (const float*)d_in[7];
    const float* M1a = (const float*)d_in[8];
    const float* b1a = (const float*)d_in[9];
    const float* M1b = (const float*)d_in[10];
    const float* b1b = (const float*)d_in[11];
    const float* Wq2 = (const float*)d_in[12];
    const float* Wk2 = (const float*)d_in[13];
    const float* Wv2 = (const float*)d_in[14];
    const float* We2 = (const float*)d_in[15];
    const float* Ws2 = (const float*)d_in[16];
    const float* M2a = (const float*)d_in[17];
    const float* b2a = (const float*)d_in[18];
    const float* M2b = (const float*)d_in[19];
    const float* b2b = (const float*)d_in[20];
    const float* Wf1 = (const float*)d_in[21];
    const float* bf1 = (const float*)d_in[22];
    const float* Wf2 = (const float*)d_in[23];
    const float* bf2 = (const float*)d_in[24];

    char* ws = (char*)d_ws;
    size_t off = 0;
    auto alloc = [&](size_t bytes) -> void* {
        void* p = ws + off;
        off = (off + bytes + 255) & ~(size_t)255;
        return p;
    };
    int* deg = (int*)alloc((size_t)NN * 4);
    int* rowstart = (int*)alloc((size_t)(NN + 1) * 4);
    int* cursor = (int*)alloc((size_t)NN * 4);
    int* bsum = (int*)alloc((size_t)NB_SCAN * 4);
    int4* rec = (int4*)alloc((size_t)NE * 16);
    u16* QKVS = (u16*)alloc((size_t)NPAD * 512 * 2);
    u16* Ha = (u16*)alloc((size_t)NPAD * 128 * 2);
    u16* Hb = (u16*)alloc((size_t)NPAD * 128 * 2);
    u16* Hc = (u16*)alloc((size_t)NPAD * 128 * 2);
    // weight order: [Wq1 Wk1 Wv1 Ws1][Wq2 Wk2 Wv2 Ws2][M1a M1b][M2a M2b][Wf1 Wf2]
    u16* WB[14];
    const int wsz[14] = {16384, 16384, 16384, 16384, 16384, 16384, 16384,
                         16384, 16384, 16384, 16384, 16384, 16384, 8192};
    for (int i = 0; i < 14; ++i) WB[i] = (u16*)alloc((size_t)wsz[i] * 2);

    const int* srcv = ei;
    const int* dstv = ei + NE;

    // CSR build
    hipMemsetAsync(deg, 0, (size_t)NN * 4, stream);
    k_hist<<<(NE + 255) / 256, 256, 0, stream>>>(dstv, deg);
    k_scan1<<<NB_SCAN, 256, 0, stream>>>(deg, rowstart, bsum);
    k_scan2<<<1, 256, 0, stream>>>(bsum);
    k_scan3<<<NB_SCAN, 256, 0, stream>>>(bsum, rowstart, cursor);
    k_scatter<<<(NE + 255) / 256, 256, 0, stream>>>(srcv, dstv, eattr, cursor, rec);

    CvtTab tab;
    const float* wsrc[14] = {Wq1, Wk1, Wv1, Ws1, Wq2, Wk2, Wv2, Ws2,
                             M1a, M1b, M2a, M2b, Wf1, Wf2};
    for (int i = 0; i < 14; ++i) { tab.e[i].s = wsrc[i]; tab.e[i].d = WB[i]; tab.e[i].n = wsz[i]; }
    k_cvt_w<<<112, 256, 0, stream>>>(tab);

    dim3 blk(256);
    dim3 grd(NPAD / 64);   // 782
    dim3 gconv(NN / 2);    // 25000

    // ----- layer 1 -----
    k_qkvs<true><<<grd, blk, 0, stream>>>(x, WB[0], QKVS);
    k_conv<<<gconv, blk, 0, stream>>>(rowstart, rec, QKVS, We1, Ha);                 // H1 = Ha
    k_mlp<8, true, false><<<grd, blk, 0, stream>>>(Ha, WB[8], b1a, b1b, Hc);         // H2 = Hc

    // ----- layer 2 -----
    k_qkvs<false><<<grd, blk, 0, stream>>>(Hc, WB[4], QKVS);
    k_conv<<<gconv, blk, 0, stream>>>(rowstart, rec, QKVS, We2, Ha);                 // H3 = Ha
    k_mlp<8, true, false><<<grd, blk, 0, stream>>>(Ha, WB[10], b2a, b2b, Hb);        // H4 = Hb

    // ----- final MLP -----
    k_mlp<4, false, true><<<grd, blk, 0, stream>>>(Hb, WB[12], bf1, bf2, d_out);
}

// Round 7
// 565.367 us; speedup vs baseline: 2.7569x; 1.0432x over previous
//
#include <hip/hip_runtime.h>
#include <hip/hip_bf16.h>
#include <math.h>

// Problem constants (fixed by the reference)
#define NN 50000
#define NE 800000
#define NPAD 50048   // 782 * 64 — tail-free GEMM tiles
#define NB_SCAN 196  // ceil(NN/256)

typedef unsigned short u16;
typedef unsigned int u32;
typedef __attribute__((ext_vector_type(8))) short short8;   // 8 bf16 (MFMA A/B frag)
typedef __attribute__((ext_vector_type(4))) float float4v;  // MFMA C/D frag

__device__ __forceinline__ float us2f(u16 u) { return __uint_as_float(((unsigned)u) << 16); }
__device__ __forceinline__ float blo(u32 u) { return __uint_as_float(u << 16); }
__device__ __forceinline__ float bhi(u32 u) { return __uint_as_float(u & 0xffff0000u); }
__device__ __forceinline__ u16 f2us(float f) {   // fp32 -> bf16 RNE
    unsigned x = __float_as_uint(f);
    return (u16)((x + 0x7FFFu + ((x >> 16) & 1u)) >> 16);
}
// tanh-gelu via sigmoid identity: 0.5*(1+tanh(u)) = sigmoid(2u)
__device__ __forceinline__ float gelu_f(float x) {
    float p = x * x;
    float t = x * fmaf(p, 0.0713548162726f, 1.5957691216057308f);  // 2u
    float e = __expf(-t);
    return x * __builtin_amdgcn_rcpf(1.0f + e);
}

__device__ __forceinline__ float4v mfma4(const u16* __restrict__ Wbase, int wrow, int m, int kb,
                                         short8 a0, short8 a1, short8 a2, short8 a3) {
    const short8* wr = (const short8*)(Wbase + (size_t)(wrow + m) * 128);
    short8 b0 = wr[kb], b1 = wr[kb + 4], b2 = wr[kb + 8], b3 = wr[kb + 12];
    float4v acc = {0.f, 0.f, 0.f, 0.f};
    acc = __builtin_amdgcn_mfma_f32_16x16x32_bf16(a0, b0, acc, 0, 0, 0);
    acc = __builtin_amdgcn_mfma_f32_16x16x32_bf16(a1, b1, acc, 0, 0, 0);
    acc = __builtin_amdgcn_mfma_f32_16x16x32_bf16(a2, b2, acc, 0, 0, 0);
    acc = __builtin_amdgcn_mfma_f32_16x16x32_bf16(a3, b3, acc, 0, 0, 0);
    return acc;
}

// ---------------- CSR build ----------------

__global__ void k_hist(const int* __restrict__ dstv, int* __restrict__ deg) {
    int e = blockIdx.x * blockDim.x + threadIdx.x;
    if (e < NE) atomicAdd(&deg[dstv[e]], 1);
}

__global__ __launch_bounds__(256) void k_scan1(const int* __restrict__ deg,
                                               int* __restrict__ rowstart,
                                               int* __restrict__ bsum) {
    __shared__ int wtot[4];
    int i = blockIdx.x * 256 + threadIdx.x;
    int lane = threadIdx.x & 63, w = threadIdx.x >> 6;
    int v = (i < NN) ? deg[i] : 0;
    int incl = v;
#pragma unroll
    for (int d = 1; d < 64; d <<= 1) {
        int tv = __shfl_up(incl, d);
        if (lane >= d) incl += tv;
    }
    if (lane == 63) wtot[w] = incl;
    __syncthreads();
    if (threadIdx.x == 0) {
        int s = 0;
#pragma unroll
        for (int j = 0; j < 4; ++j) { int t = wtot[j]; wtot[j] = s; s += t; }
        bsum[blockIdx.x] = s;
    }
    __syncthreads();
    if (i < NN) rowstart[i] = incl - v + wtot[w];
}

__global__ __launch_bounds__(256) void k_scan2(int* __restrict__ bsum) {
    __shared__ int wtot[4];
    int t = threadIdx.x;
    int lane = t & 63, w = t >> 6;
    int v = (t < NB_SCAN) ? bsum[t] : 0;
    int incl = v;
#pragma unroll
    for (int d = 1; d < 64; d <<= 1) {
        int tv = __shfl_up(incl, d);
        if (lane >= d) incl += tv;
    }
    if (lane == 63) wtot[w] = incl;
    __syncthreads();
    if (t == 0) {
        int s = 0;
#pragma unroll
        for (int j = 0; j < 4; ++j) { int tt = wtot[j]; wtot[j] = s; s += tt; }
    }
    __syncthreads();
    if (t < NB_SCAN) bsum[t] = incl - v + wtot[w];
}

__global__ void k_scan3(const int* __restrict__ bsum, int* __restrict__ rowstart,
                        int* __restrict__ cursor) {
    int i = blockIdx.x * 256 + threadIdx.x;
    if (i < NN) {
        int v = rowstart[i] + bsum[blockIdx.x];
        rowstart[i] = v;
        cursor[i] = v;
    }
    if (i == 0) rowstart[NN] = NE;
}

__global__ void k_scatter(const int* __restrict__ srcv, const int* __restrict__ dstv,
                          const float* __restrict__ eattr, int* __restrict__ cursor,
                          int4* __restrict__ rec) {
    int e = blockIdx.x * blockDim.x + threadIdx.x;
    if (e >= NE) return;
    int dst = dstv[e];
    int pos = atomicAdd(&cursor[dst], 1);
    int4 r;
    r.x = srcv[e];
    r.y = __float_as_int(eattr[e * 3 + 0]);
    r.z = __float_as_int(eattr[e * 3 + 1]);
    r.w = __float_as_int(eattr[e * 3 + 2]);
    rec[pos] = r;
}

// ---------------- weight fp32->bf16 ----------------

struct CvtEnt { const float* s; u16* d; int n; };
struct CvtTab { CvtEnt e[14]; };
__global__ void k_cvt_w(CvtTab tab) {
    CvtEnt E = tab.e[blockIdx.x >> 3];
    int chunk = blockIdx.x & 7;
    int per = E.n >> 3;
    int lo = chunk * per, hi = lo + per;
    for (int i = lo + threadIdx.x; i < hi; i += blockDim.x) E.d[i] = f2us(E.s[i]);
}

// ---------------- layer-1 QKVS GEMM (A = fp32 x) ----------------
// Out row (stride 512 u16): [q 0..127 | kv interleaved 128..383 | s 384..511]
// kv[4p+0..3] = {k[2p],k[2p+1],v[2p],v[2p+1]}.

__global__ __launch_bounds__(256) void k_qkvs1(const float* __restrict__ Ain,
                                               const u16* __restrict__ W,
                                               u16* __restrict__ QKVS) {
    __shared__ u16 tile[64 * 264];
    int tid = threadIdx.x;
    int l = tid & 63, w = tid >> 6, m = l & 15, kb = l >> 4;
    int r0 = blockIdx.x * 64;
    int ar = r0 + w * 16 + m;

    short8 a0, a1, a2, a3;
    {
        const float* ap = Ain + (size_t)ar * 128;
        bool ok = ar < NN;
        short8* dsts[4] = {&a0, &a1, &a2, &a3};
#pragma unroll
        for (int i = 0; i < 4; ++i) {
            short8 r;
            if (ok) {
                const float* p = ap + (kb + i * 4) * 8;
                float4 f0 = *(const float4*)p;
                float4 f1 = *(const float4*)(p + 4);
                r[0]=(short)f2us(f0.x); r[1]=(short)f2us(f0.y); r[2]=(short)f2us(f0.z); r[3]=(short)f2us(f0.w);
                r[4]=(short)f2us(f1.x); r[5]=(short)f2us(f1.y); r[6]=(short)f2us(f1.z); r[7]=(short)f2us(f1.w);
            } else {
#pragma unroll
                for (int j = 0; j < 8; ++j) r[j] = 0;
            }
            *dsts[i] = r;
        }
    }
    int lrow = w * 16 + kb * 4;

    // ---- q ----
#pragma unroll
    for (int tt = 0; tt < 8; ++tt) {
        float4v acc = mfma4(W, tt * 16, m, kb, a0, a1, a2, a3);
#pragma unroll
        for (int r = 0; r < 4; ++r) tile[(lrow + r) * 264 + tt * 16 + m] = f2us(acc[r]);
    }
    __syncthreads();
#pragma unroll
    for (int it = 0; it < 4; ++it) {
        int q = (it * 256 + tid) * 8;
        int row = q >> 7, col = q & 127;
        *(uint4*)(QKVS + (size_t)(r0 + row) * 512 + col) = *(const uint4*)&tile[row * 264 + col];
    }
    __syncthreads();
    // ---- k + v interleaved ----
#pragma unroll
    for (int tt = 0; tt < 8; ++tt) {
        float4v acc = mfma4(W, 128 + tt * 16, m, kb, a0, a1, a2, a3);
        int c = tt * 32 + 4 * (m >> 1) + (m & 1);
#pragma unroll
        for (int r = 0; r < 4; ++r) tile[(lrow + r) * 264 + c] = f2us(acc[r]);
    }
#pragma unroll
    for (int tt = 0; tt < 8; ++tt) {
        float4v acc = mfma4(W, 256 + tt * 16, m, kb, a0, a1, a2, a3);
        int c = tt * 32 + 4 * (m >> 1) + (m & 1) + 2;
#pragma unroll
        for (int r = 0; r < 4; ++r) tile[(lrow + r) * 264 + c] = f2us(acc[r]);
    }
    __syncthreads();
#pragma unroll
    for (int it = 0; it < 8; ++it) {
        int q = (it * 256 + tid) * 8;
        int row = q >> 8, col = q & 255;
        *(uint4*)(QKVS + (size_t)(r0 + row) * 512 + 128 + col) = *(const uint4*)&tile[row * 264 + col];
    }
    __syncthreads();
    // ---- s ----
#pragma unroll
    for (int tt = 0; tt < 8; ++tt) {
        float4v acc = mfma4(W, 384 + tt * 16, m, kb, a0, a1, a2, a3);
#pragma unroll
        for (int r = 0; r < 4; ++r) tile[(lrow + r) * 264 + tt * 16 + m] = f2us(acc[r]);
    }
    __syncthreads();
#pragma unroll
    for (int it = 0; it < 4; ++it) {
        int q = (it * 256 + tid) * 8;
        int row = q >> 7, col = q & 127;
        *(uint4*)(QKVS + (size_t)(r0 + row) * 512 + 384 + col) = *(const uint4*)&tile[row * 264 + col];
    }
}

// ---------------- fused MLP + next-layer QKVS ----------------
// H2 = A + gelu(gelu(A@M1a+b1)@M1b+b2) computed per 64-row tile entirely in LDS,
// then QKVS2 = H2 @ [Wq|Wk|Wv|Ws]^T staged section-by-section through t1.

__global__ __launch_bounds__(256) void k_mlp_qkvs(const u16* __restrict__ Ain,
                                                  const u16* __restrict__ Wm,
                                                  const float* __restrict__ bias1,
                                                  const float* __restrict__ bias2,
                                                  const u16* __restrict__ Wq,
                                                  u16* __restrict__ QKVS) {
    __shared__ u16 sh[64 * 136];
    __shared__ u16 t1[64 * 136];
    int tid = threadIdx.x;
    int l = tid & 63, w = tid >> 6, m = l & 15, kb = l >> 4;
    int r0 = blockIdx.x * 64;
    int lrow = w * 16 + kb * 4;

    const short8* arow = (const short8*)(Ain + (size_t)(r0 + w * 16 + m) * 128);
    short8 a0 = arow[kb], a1 = arow[kb + 4], a2 = arow[kb + 8], a3 = arow[kb + 12];
    {   // stage A (residual source) into sh, row layout
        u16* shrow = sh + (w * 16 + m) * 136;
        *(short8*)(shrow + kb * 8) = a0;
        *(short8*)(shrow + 32 + kb * 8) = a1;
        *(short8*)(shrow + 64 + kb * 8) = a2;
        *(short8*)(shrow + 96 + kb * 8) = a3;
    }
    // GEMM1 -> t1 (gelu)
#pragma unroll
    for (int tt = 0; tt < 8; ++tt) {
        float4v acc = mfma4(Wm, tt * 16, m, kb, a0, a1, a2, a3);
        float bv = bias1[tt * 16 + m];
#pragma unroll
        for (int r = 0; r < 4; ++r)
            t1[(lrow + r) * 136 + tt * 16 + m] = f2us(gelu_f(acc[r] + bv));
    }
    __syncthreads();
    const u16* t1r = t1 + (w * 16 + m) * 136;
    short8 c0 = *(const short8*)(t1r + kb * 8);
    short8 c1 = *(const short8*)(t1r + 32 + kb * 8);
    short8 c2 = *(const short8*)(t1r + 64 + kb * 8);
    short8 c3 = *(const short8*)(t1r + 96 + kb * 8);
    // GEMM2 + residual -> sh becomes H2 (each position read+written by its owner lane)
#pragma unroll
    for (int tt = 0; tt < 8; ++tt) {
        float4v acc = mfma4(Wm + 16384, tt * 16, m, kb, c0, c1, c2, c3);
        float bv = bias2[tt * 16 + m];
#pragma unroll
        for (int r = 0; r < 4; ++r) {
            int idx = (lrow + r) * 136 + tt * 16 + m;
            float hv = gelu_f(acc[r] + bv) + us2f(sh[idx]);
            sh[idx] = f2us(hv);
        }
    }
    __syncthreads();
    const u16* shr = sh + (w * 16 + m) * 136;
    short8 h0 = *(const short8*)(shr + kb * 8);
    short8 h1 = *(const short8*)(shr + 32 + kb * 8);
    short8 h2 = *(const short8*)(shr + 64 + kb * 8);
    short8 h3 = *(const short8*)(shr + 96 + kb * 8);

    // ---- q section (W rows 0..127) ----
#pragma unroll
    for (int tt = 0; tt < 8; ++tt) {
        float4v acc = mfma4(Wq, tt * 16, m, kb, h0, h1, h2, h3);
#pragma unroll
        for (int r = 0; r < 4; ++r) t1[(lrow + r) * 136 + tt * 16 + m] = f2us(acc[r]);
    }
    __syncthreads();
#pragma unroll
    for (int it = 0; it < 4; ++it) {
        int q = (it * 256 + tid) * 8;
        int row = q >> 7, col = q & 127;
        *(uint4*)(QKVS + (size_t)(r0 + row) * 512 + col) = *(const uint4*)&t1[row * 136 + col];
    }
    __syncthreads();
    // ---- kv-lo: k tiles 0..3 (rows 128..191) + v tiles 0..3 (rows 256..319) ----
#pragma unroll
    for (int tt = 0; tt < 4; ++tt) {
        float4v acc = mfma4(Wq, 128 + tt * 16, m, kb, h0, h1, h2, h3);
        int c = tt * 32 + 4 * (m >> 1) + (m & 1);
#pragma unroll
        for (int r = 0; r < 4; ++r) t1[(lrow + r) * 136 + c] = f2us(acc[r]);
    }
#pragma unroll
    for (int tt = 0; tt < 4; ++tt) {
        float4v acc = mfma4(Wq, 256 + tt * 16, m, kb, h0, h1, h2, h3);
        int c = tt * 32 + 4 * (m >> 1) + (m & 1) + 2;
#pragma unroll
        for (int r = 0; r < 4; ++r) t1[(lrow + r) * 136 + c] = f2us(acc[r]);
    }
    __syncthreads();
#pragma unroll
    for (int it = 0; it < 4; ++it) {
        int q = (it * 256 + tid) * 8;
        int row = q >> 7, col = q & 127;
        *(uint4*)(QKVS + (size_t)(r0 + row) * 512 + 128 + col) = *(const uint4*)&t1[row * 136 + col];
    }
    __syncthreads();
    // ---- kv-hi: k tiles 4..7 (rows 192..255) + v tiles 4..7 (rows 320..383) ----
#pragma unroll
    for (int tt = 0; tt < 4; ++tt) {
        float4v acc = mfma4(Wq, 192 + tt * 16, m, kb, h0, h1, h2, h3);
        int c = tt * 32 + 4 * (m >> 1) + (m & 1);
#pragma unroll
        for (int r = 0; r < 4; ++r) t1[(lrow + r) * 136 + c] = f2us(acc[r]);
    }
#pragma unroll
    for (int tt = 0; tt < 4; ++tt) {
        float4v acc = mfma4(Wq, 320 + tt * 16, m, kb, h0, h1, h2, h3);
        int c = tt * 32 + 4 * (m >> 1) + (m & 1) + 2;
#pragma unroll
        for (int r = 0; r < 4; ++r) t1[(lrow + r) * 136 + c] = f2us(acc[r]);
    }
    __syncthreads();
#pragma unroll
    for (int it = 0; it < 4; ++it) {
        int q = (it * 256 + tid) * 8;
        int row = q >> 7, col = q & 127;
        *(uint4*)(QKVS + (size_t)(r0 + row) * 512 + 256 + col) = *(const uint4*)&t1[row * 136 + col];
    }
    __syncthreads();
    // ---- s section (rows 384..511) ----
#pragma unroll
    for (int tt = 0; tt < 8; ++tt) {
        float4v acc = mfma4(Wq, 384 + tt * 16, m, kb, h0, h1, h2, h3);
#pragma unroll
        for (int r = 0; r < 4; ++r) t1[(lrow + r) * 136 + tt * 16 + m] = f2us(acc[r]);
    }
    __syncthreads();
#pragma unroll
    for (int it = 0; it < 4; ++it) {
        int q = (it * 256 + tid) * 8;
        int row = q >> 7, col = q & 127;
        *(uint4*)(QKVS + (size_t)(r0 + row) * 512 + 384 + col) = *(const uint4*)&t1[row * 136 + col];
    }
}

// ---------------- fused MLP + final MLP ----------------
// H4 = A + gelu(gelu(A@M2a+b)@M2b+b); out = gelu(gelu(H4@Wf1+bf1)@Wf2+bf2) (fp32, 64 cols)

__global__ __launch_bounds__(256) void k_mlp_final(const u16* __restrict__ Ain,
                                                   const u16* __restrict__ Wm,
                                                   const float* __restrict__ bias1,
                                                   const float* __restrict__ bias2,
                                                   const u16* __restrict__ Wf,
                                                   const float* __restrict__ bf1,
                                                   const float* __restrict__ bf2,
                                                   float* __restrict__ outp) {
    __shared__ u16 sh[64 * 136];
    __shared__ u16 t1[64 * 136];
    int tid = threadIdx.x;
    int l = tid & 63, w = tid >> 6, m = l & 15, kb = l >> 4;
    int r0 = blockIdx.x * 64;
    int lrow = w * 16 + kb * 4;

    const short8* arow = (const short8*)(Ain + (size_t)(r0 + w * 16 + m) * 128);
    short8 a0 = arow[kb], a1 = arow[kb + 4], a2 = arow[kb + 8], a3 = arow[kb + 12];
    {
        u16* shrow = sh + (w * 16 + m) * 136;
        *(short8*)(shrow + kb * 8) = a0;
        *(short8*)(shrow + 32 + kb * 8) = a1;
        *(short8*)(shrow + 64 + kb * 8) = a2;
        *(short8*)(shrow + 96 + kb * 8) = a3;
    }
#pragma unroll
    for (int tt = 0; tt < 8; ++tt) {
        float4v acc = mfma4(Wm, tt * 16, m, kb, a0, a1, a2, a3);
        float bv = bias1[tt * 16 + m];
#pragma unroll
        for (int r = 0; r < 4; ++r)
            t1[(lrow + r) * 136 + tt * 16 + m] = f2us(gelu_f(acc[r] + bv));
    }
    __syncthreads();
    const u16* t1r = t1 + (w * 16 + m) * 136;
    short8 c0 = *(const short8*)(t1r + kb * 8);
    short8 c1 = *(const short8*)(t1r + 32 + kb * 8);
    short8 c2 = *(const short8*)(t1r + 64 + kb * 8);
    short8 c3 = *(const short8*)(t1r + 96 + kb * 8);
#pragma unroll
    for (int tt = 0; tt < 8; ++tt) {
        float4v acc = mfma4(Wm + 16384, tt * 16, m, kb, c0, c1, c2, c3);
        float bv = bias2[tt * 16 + m];
#pragma unroll
        for (int r = 0; r < 4; ++r) {
            int idx = (lrow + r) * 136 + tt * 16 + m;
            float hv = gelu_f(acc[r] + bv) + us2f(sh[idx]);
            sh[idx] = f2us(hv);
        }
    }
    __syncthreads();
    const u16* shr = sh + (w * 16 + m) * 136;
    short8 h0 = *(const short8*)(shr + kb * 8);
    short8 h1 = *(const short8*)(shr + 32 + kb * 8);
    short8 h2 = *(const short8*)(shr + 64 + kb * 8);
    short8 h3 = *(const short8*)(shr + 96 + kb * 8);
    // G3 = gelu(H4@Wf1+bf1) -> t1
#pragma unroll
    for (int tt = 0; tt < 8; ++tt) {
        float4v acc = mfma4(Wf, tt * 16, m, kb, h0, h1, h2, h3);
        float bv = bf1[tt * 16 + m];
#pragma unroll
        for (int r = 0; r < 4; ++r)
            t1[(lrow + r) * 136 + tt * 16 + m] = f2us(gelu_f(acc[r] + bv));
    }
    __syncthreads();
    short8 f0 = *(const short8*)(t1r + kb * 8);
    short8 f1 = *(const short8*)(t1r + 32 + kb * 8);
    short8 f2 = *(const short8*)(t1r + 64 + kb * 8);
    short8 f3 = *(const short8*)(t1r + 96 + kb * 8);
    __syncthreads();   // all f-frag reads done before t1 reuse
    // G4 = gelu(G3@Wf2+bf2), 64 cols -> stage t1
#pragma unroll
    for (int tt = 0; tt < 4; ++tt) {
        float4v acc = mfma4(Wf + 16384, tt * 16, m, kb, f0, f1, f2, f3);
        float bv = bf2[tt * 16 + m];
#pragma unroll
        for (int r = 0; r < 4; ++r)
            t1[(lrow + r) * 136 + tt * 16 + m] = f2us(gelu_f(acc[r] + bv));
    }
    __syncthreads();
#pragma unroll
    for (int it = 0; it < 2; ++it) {
        int q = (it * 256 + tid) * 8;
        int row = q >> 6, col = q & 63;
        int grow = r0 + row;
        if (grow < NN) {
            uint4 pk = *(const uint4*)&t1[row * 136 + col];
            const u16* pv = (const u16*)&pk;
            float* po = outp + (size_t)grow * 64 + col;
            float4 o0 = {us2f(pv[0]), us2f(pv[1]), us2f(pv[2]), us2f(pv[3])};
            float4 o1 = {us2f(pv[4]), us2f(pv[5]), us2f(pv[6]), us2f(pv[7])};
            *(float4*)po = o0;
            *(float4*)(po + 4) = o1;
        }
    }
}

// ---------------- TransformerConv aggregation ----------------
// 1 wave/node, 2 cols/lane. Algebraic factoring: alpha = (q.k_src + a.g)*scale,
// g_j = sum_c q_c We[c][j] (per head, precomputed); out = (sum p*v + We.S)*inv + skip,
// S_j = sum_e p_e a_j. No-max softmax (exp clamp 80).

__global__ __launch_bounds__(256) void k_conv(const int* __restrict__ rowstart,
                                              const int4* __restrict__ rec,
                                              const u16* __restrict__ qkvs,
                                              const float* __restrict__ We,
                                              u16* __restrict__ out) {
    int n = blockIdx.x * 4 + (threadIdx.x >> 6);
    int l = threadIdx.x & 63;
    int c0 = (l >> 4) * 32 + (l & 15) * 2;
    const u16* qrow = qkvs + (size_t)n * 512;
    u32 qu = *(const u32*)(qrow + c0);
    float q0 = blo(qu), q1 = bhi(qu);
    float we00 = We[c0 * 3 + 0], we01 = We[c0 * 3 + 1], we02 = We[c0 * 3 + 2];
    float we10 = We[c0 * 3 + 3], we11 = We[c0 * 3 + 4], we12 = We[c0 * 3 + 5];
    // g_j = per-head reduction of q_c * We[c][j]
    float g0 = fmaf(q1, we10, q0 * we00);
    float g1 = fmaf(q1, we11, q0 * we01);
    float g2 = fmaf(q1, we12, q0 * we02);
#pragma unroll
    for (int d = 8; d >= 1; d >>= 1) {
        g0 += __shfl_xor(g0, d);
        g1 += __shfl_xor(g1, d);
        g2 += __shfl_xor(g2, d);
    }
    int e0 = rowstart[n], e1 = rowstart[n + 1];
    float ss = 0.f, o0 = 0.f, o1 = 0.f, S0 = 0.f, S1 = 0.f, S2 = 0.f;

    auto edge = [&](int4 r, uint2 kv) {
        float part = fmaf(q1, bhi(kv.x), q0 * blo(kv.x));
        part += __shfl_xor(part, 8);
        part += __shfl_xor(part, 4);
        part += __shfl_xor(part, 2);
        part += __shfl_xor(part, 1);
        float ea0 = __int_as_float(r.y), ea1 = __int_as_float(r.z), ea2 = __int_as_float(r.w);
        float alpha = fmaf(ea2, g2, fmaf(ea1, g1, fmaf(ea0, g0, part))) * 0.17677669529663687f;
        float p = __expf(fminf(alpha, 80.f));
        o0 = fmaf(p, blo(kv.y), o0);
        o1 = fmaf(p, bhi(kv.y), o1);
        ss += p;
        S0 = fmaf(p, ea0, S0);
        S1 = fmaf(p, ea1, S1);
        S2 = fmaf(p, ea2, S2);
    };

    int e = e0;
    if ((e1 - e0) & 1) {
        int4 r = rec[e];
        uint2 kv = *(const uint2*)(qkvs + (size_t)r.x * 512 + 128 + c0 * 2);
        edge(r, kv);
        ++e;
    }
    for (; e < e1; e += 2) {
        int4 ra = rec[e], rb = rec[e + 1];
        uint2 kva = *(const uint2*)(qkvs + (size_t)ra.x * 512 + 128 + c0 * 2);
        uint2 kvb = *(const uint2*)(qkvs + (size_t)rb.x * 512 + 128 + c0 * 2);
        edge(ra, kva);
        edge(rb, kvb);
    }
    float inv = __builtin_amdgcn_rcpf(fmaxf(ss, 1e-16f));
    o0 = fmaf(we02, S2, fmaf(we01, S1, fmaf(we00, S0, o0)));
    o1 = fmaf(we12, S2, fmaf(we11, S1, fmaf(we10, S0, o1)));
    u32 su = *(const u32*)(qrow + 384 + c0);
    float r0v = fmaf(o0, inv, blo(su));
    float r1v = fmaf(o1, inv, bhi(su));
    u32 ou = (u32)f2us(r0v) | ((u32)f2us(r1v) << 16);
    *(u32*)(out + (size_t)n * 128 + c0) = ou;
}

// ---------------- launcher ----------------

extern "C" void kernel_launch(void* const* d_in, const int* in_sizes, int n_in,
                              void* d_out, int out_size, void* d_ws, size_t ws_size,
                              hipStream_t stream) {
    const float* x = (const float*)d_in[0];
    const int* ei = (const int*)d_in[1];
    const float* eattr = (const float*)d_in[2];
    const float* Wq1 = (const float*)d_in[3];
    const float* Wk1 = (const float*)d_in[4];
    const float* Wv1 = (const float*)d_in[5];
    const float* We1 = (const float*)d_in[6];
    const float* Ws1 = (const float*)d_in[7];
    const float* M1a = (const float*)d_in[8];
    const float* b1a = (const float*)d_in[9];
    const float* M1b = (const float*)d_in[10];
    const float* b1b = (const float*)d_in[11];
    const float* Wq2 = (const float*)d_in[12];
    const float* Wk2 = (const float*)d_in[13];
    const float* Wv2 = (const float*)d_in[14];
    const float* We2 = (const float*)d_in[15];
    const float* Ws2 = (const float*)d_in[16];
    const float* M2a = (const float*)d_in[17];
    const float* b2a = (const float*)d_in[18];
    const float* M2b = (const float*)d_in[19];
    const float* b2b = (const float*)d_in[20];
    const float* Wf1 = (const float*)d_in[21];
    const float* bf1 = (const float*)d_in[22];
    const float* Wf2 = (const float*)d_in[23];
    const float* bf2 = (const float*)d_in[24];

    char* ws = (char*)d_ws;
    size_t off = 0;
    auto alloc = [&](size_t bytes) -> void* {
        void* p = ws + off;
        off = (off + bytes + 255) & ~(size_t)255;
        return p;
    };
    int* deg = (int*)alloc((size_t)NN * 4);
    int* rowstart = (int*)alloc((size_t)(NN + 1) * 4);
    int* cursor = (int*)alloc((size_t)NN * 4);
    int* bsum = (int*)alloc((size_t)NB_SCAN * 4);
    int4* rec = (int4*)alloc((size_t)NE * 16);
    u16* QKVS = (u16*)alloc((size_t)NPAD * 512 * 2);
    u16* Ha = (u16*)alloc((size_t)NPAD * 128 * 2);
    // weight order: [Wq1 Wk1 Wv1 Ws1][Wq2 Wk2 Wv2 Ws2][M1a M1b][M2a M2b][Wf1 Wf2]
    u16* WB[14];
    const int wsz[14] = {16384, 16384, 16384, 16384, 16384, 16384, 16384,
                         16384, 16384, 16384, 16384, 16384, 16384, 8192};
    for (int i = 0; i < 14; ++i) WB[i] = (u16*)alloc((size_t)wsz[i] * 2);

    const int* srcv = ei;
    const int* dstv = ei + NE;

    // CSR build
    hipMemsetAsync(deg, 0, (size_t)NN * 4, stream);
    k_hist<<<(NE + 255) / 256, 256, 0, stream>>>(dstv, deg);
    k_scan1<<<NB_SCAN, 256, 0, stream>>>(deg, rowstart, bsum);
    k_scan2<<<1, 256, 0, stream>>>(bsum);
    k_scan3<<<NB_SCAN, 256, 0, stream>>>(bsum, rowstart, cursor);
    k_scatter<<<(NE + 255) / 256, 256, 0, stream>>>(srcv, dstv, eattr, cursor, rec);

    CvtTab tab;
    const float* wsrc[14] = {Wq1, Wk1, Wv1, Ws1, Wq2, Wk2, Wv2, Ws2,
                             M1a, M1b, M2a, M2b, Wf1, Wf2};
    for (int i = 0; i < 14; ++i) { tab.e[i].s = wsrc[i]; tab.e[i].d = WB[i]; tab.e[i].n = wsz[i]; }
    k_cvt_w<<<112, 256, 0, stream>>>(tab);

    dim3 blk(256);
    dim3 grd(NPAD / 64);   // 782
    dim3 gconv(NN / 4);    // 12500

    // layer 1
    k_qkvs1<<<grd, blk, 0, stream>>>(x, WB[0], QKVS);
    k_conv<<<gconv, blk, 0, stream>>>(rowstart, rec, QKVS, We1, Ha);            // H1 = Ha
    // MLP1 + layer-2 QKVS (H2 never hits HBM)
    k_mlp_qkvs<<<grd, blk, 0, stream>>>(Ha, WB[8], b1a, b1b, WB[4], QKVS);
    k_conv<<<gconv, blk, 0, stream>>>(rowstart, rec, QKVS, We2, Ha);            // H3 = Ha
    // MLP2 + final MLP (H4 never hits HBM)
    k_mlp_final<<<grd, blk, 0, stream>>>(Ha, WB[10], b2a, b2b, WB[12], bf1, bf2, (float*)d_out);
}